// Round 4
// baseline (604.458 us; speedup 1.0000x reference)
//
#include <hip/hip_runtime.h>

#define NN 100000
#define NE 1600000
#define DD 128
#define HH 16
#define CC 40
#define LL 3

__device__ __forceinline__ float4 f4fma(float s, float4 w, float4 a) {
    a.x = fmaf(s, w.x, a.x); a.y = fmaf(s, w.y, a.y);
    a.z = fmaf(s, w.z, a.z); a.w = fmaf(s, w.w, a.w);
    return a;
}

// swizzle for a [16][32]-float4 LDS array read at dw = p*8+dq by lanes p=0..3:
// rotate within the 8-quad block so the 4 lanes land on disjoint banks.
__device__ __forceinline__ int swzW2(int dw) {
    return (dw & 24) | ((dw + (dw >> 3)) & 7);
}

__global__ void build_rowptr(const int* __restrict__ row, int* __restrict__ rp) {
    int i = blockIdx.x * blockDim.x + threadIdx.x;
    if (i > NN) return;
    int lo = 0, hi = NE;
    while (lo < hi) { int m = (lo + hi) >> 1; if (row[m] < i) lo = m + 1; else hi = m; }
    rp[i] = lo;
}

__global__ void zero_buf(float* __restrict__ s, int n) {
    int i = blockIdx.x * 256 + threadIdx.x;
    if (i < n) s[i] = 0.f;
}

// ---- Y = X @ W  (N x 128)@(128 x 16); 4 threads/node, shfl reduce ----
__launch_bounds__(256)
__global__ void gemm_dh_reg(const float* __restrict__ X, const float* __restrict__ W,
                            float* __restrict__ Y) {
    __shared__ float4 Ws[DD * 4];   // row d, quad q stored at d*4 + ((q + (d>>5)) & 3)
    int t = threadIdx.x;
    for (int i = t; i < DD * 4; i += 256) {
        int d = i >> 2, q = i & 3;
        Ws[d * 4 + ((q + (d >> 5)) & 3)] = ((const float4*)W)[i];
    }
    __syncthreads();
    int node = blockIdx.x * 64 + (t >> 2);
    int p = t & 2, pp = t & 3;
    (void)p;
    if (node >= NN) return;
    const float4* X4 = (const float4*)X + (size_t)node * 32 + pp * 8;
    float4 yy[4] = {{0,0,0,0},{0,0,0,0},{0,0,0,0},{0,0,0,0}};
    #pragma unroll
    for (int dq = 0; dq < 8; dq++) {
        float4 xv = X4[dq];
        float xs[4] = {xv.x, xv.y, xv.z, xv.w};
        #pragma unroll
        for (int j = 0; j < 4; j++) {
            int d = pp * 32 + dq * 4 + j;
            #pragma unroll
            for (int q = 0; q < 4; q++)
                yy[q] = f4fma(xs[j], Ws[d * 4 + ((q + pp) & 3)], yy[q]);
        }
    }
    #pragma unroll
    for (int q = 0; q < 4; q++) {
        yy[q].x += __shfl_xor(yy[q].x, 1); yy[q].y += __shfl_xor(yy[q].y, 1);
        yy[q].z += __shfl_xor(yy[q].z, 1); yy[q].w += __shfl_xor(yy[q].w, 1);
        yy[q].x += __shfl_xor(yy[q].x, 2); yy[q].y += __shfl_xor(yy[q].y, 2);
        yy[q].z += __shfl_xor(yy[q].z, 2); yy[q].w += __shfl_xor(yy[q].w, 2);
    }
    ((float4*)Y)[(size_t)node * 4 + pp] = yy[pp];
}

// ---- out[n][0:16] = sum_e vals[e]*hin[col[e]][0:16]; 16 lanes/node ----
template <bool RELU, bool BIAS>
__launch_bounds__(256)
__global__ void spmm16(const int* __restrict__ rp, const int* __restrict__ col,
                       const float* __restrict__ vals, const float* __restrict__ hin,
                       const float* __restrict__ bias, float* __restrict__ out) {
    int node = blockIdx.x * 16 + (threadIdx.x >> 4);
    int f = threadIdx.x & 3;          // feature quad
    int q = (threadIdx.x >> 2) & 3;   // edge partition
    if (node >= NN) return;
    int s = rp[node], e = rp[node + 1];
    const float4* h4 = (const float4*)hin;
    float4 acc = {0, 0, 0, 0};
    for (int j = s + q; j < e; j += 4) {
        int c = col[j]; float v = vals[j];
        acc = f4fma(v, h4[c * 4 + f], acc);
    }
    acc.x += __shfl_xor(acc.x, 4); acc.y += __shfl_xor(acc.y, 4);
    acc.z += __shfl_xor(acc.z, 4); acc.w += __shfl_xor(acc.w, 4);
    acc.x += __shfl_xor(acc.x, 8); acc.y += __shfl_xor(acc.y, 8);
    acc.z += __shfl_xor(acc.z, 8); acc.w += __shfl_xor(acc.w, 8);
    if (q == 0) {
        if (BIAS) {
            float4 b = ((const float4*)bias)[f];
            acc.x += b.x; acc.y += b.y; acc.z += b.z; acc.w += b.w;
        }
        if (RELU) {
            acc.x = fmaxf(acc.x, 0.f); acc.y = fmaxf(acc.y, 0.f);
            acc.z = fmaxf(acc.z, 0.f); acc.w = fmaxf(acc.w, 0.f);
        }
        ((float4*)out)[(size_t)node * 4 + f] = acc;
    }
}

// GS[0..255] = G = U^T U, GS[256..271] = colsum(U)
__launch_bounds__(256)
__global__ void stats_gram(const float* __restrict__ U, float* __restrict__ GS) {
    __shared__ float Us[64 * 20];
    int t = threadIdx.x;
    int k = t & 15, kp = t >> 4;
    float g = 0.f, s = 0.f;
    const int npb = (NN + gridDim.x - 1) / gridDim.x;
    int n0 = blockIdx.x * npb;
    int n1 = min(n0 + npb, NN);
    for (int nb = n0; nb < n1; nb += 64) {
        int cnt = min(64, n1 - nb);
        __syncthreads();
        for (int i = t; i < cnt * 4; i += 256) {
            int r = i >> 2, qq = i & 3;
            ((float4*)&Us[r * 20])[qq] = ((const float4*)(U + (size_t)(nb + r) * HH))[qq];
        }
        __syncthreads();
        for (int n = 0; n < cnt; n++) {
            float a = Us[n * 20 + k];
            float b = Us[n * 20 + kp];
            g = fmaf(a, b, g);
            s += a;
        }
    }
    atomicAdd(&GS[kp * 16 + k], g);
    if (kp == 0) atomicAdd(&GS[256 + k], s);
}

// ---- Y = relu(BN(U@W2 + b2)) @ W1n ; 4 threads/node, BN stats from G,s ----
__launch_bounds__(256)
__global__ void fused_mid(const float* __restrict__ U, const float* __restrict__ GS,
                          const float* __restrict__ W2, const float* __restrict__ b2,
                          const float* __restrict__ gamma, const float* __restrict__ beta,
                          const float* __restrict__ W1n, float* __restrict__ Y) {
    __shared__ float4 W2s[HH * 32];   // (k,dw) at k*32 + swzW2(dw)
    __shared__ float4 W1s[DD * 4];    // (d,q)  at d*4 + ((q + (d>>5)) & 3)
    __shared__ float4 SC4[32], SH4[32];  // sc/sh quads, swzW2 layout
    __shared__ float  Gs[272];
    int t = threadIdx.x;
    for (int i = t; i < HH * 32; i += 256) {
        int k = i >> 5, dw = i & 31;
        W2s[k * 32 + swzW2(dw)] = ((const float4*)W2)[i];
    }
    for (int i = t; i < DD * 4; i += 256) {
        int d = i >> 2, q = i & 3;
        W1s[d * 4 + ((q + (d >> 5)) & 3)] = ((const float4*)W1n)[i];
    }
    for (int i = t; i < 272; i += 256) Gs[i] = GS[i];
    __syncthreads();
    if (t < DD) {
        int d = t;
        float w[16];
        #pragma unroll
        for (int k = 0; k < 16; k++) w[k] = W2[k * DD + d];
        float sdot = 0.f, quad = 0.f;
        #pragma unroll
        for (int k = 0; k < 16; k++) {
            sdot = fmaf(Gs[256 + k], w[k], sdot);
            float vk = 0.f;
            #pragma unroll
            for (int kp = 0; kp < 16; kp++) vk = fmaf(Gs[k * 16 + kp], w[kp], vk);
            quad = fmaf(w[k], vk, quad);
        }
        float b = b2[d];
        float sumH  = sdot + (float)NN * b;
        float sumsq = quad + 2.f * b * sdot + (float)NN * b * b;
        float mean = sumH * (1.f / NN);
        float var  = sumsq * (1.f / NN) - mean * mean;
        float inv  = rsqrtf(var + 1e-5f);
        float g = gamma[d] * inv;
        int dw = d >> 2, j = d & 3, loc = swzW2(dw);
        ((float*)&SC4[loc])[j] = g;
        ((float*)&SH4[loc])[j] = (b - mean) * g + beta[d];
    }
    __syncthreads();
    int node = blockIdx.x * 64 + (t >> 2);
    int p = t & 3;
    if (node >= NN) return;
    float u[16];
    {
        const float4* up = (const float4*)(U + (size_t)node * HH);
        float4 a = up[0], b = up[1], c = up[2], d = up[3];
        u[0]=a.x; u[1]=a.y; u[2]=a.z; u[3]=a.w; u[4]=b.x; u[5]=b.y; u[6]=b.z; u[7]=b.w;
        u[8]=c.x; u[9]=c.y; u[10]=c.z; u[11]=c.w; u[12]=d.x; u[13]=d.y; u[14]=d.z; u[15]=d.w;
    }
    float4 yy[4] = {{0,0,0,0},{0,0,0,0},{0,0,0,0},{0,0,0,0}};
    #pragma unroll
    for (int dq = 0; dq < 8; dq++) {
        int sdw = p * 8 + ((dq + p) & 7);   // swzW2(p*8+dq)
        float4 h = {0, 0, 0, 0};
        #pragma unroll
        for (int k = 0; k < 16; k++) h = f4fma(u[k], W2s[k * 32 + sdw], h);
        float4 s4 = SC4[sdw], t4 = SH4[sdw];
        h.x = fmaxf(fmaf(h.x, s4.x, t4.x), 0.f); h.y = fmaxf(fmaf(h.y, s4.y, t4.y), 0.f);
        h.z = fmaxf(fmaf(h.z, s4.z, t4.z), 0.f); h.w = fmaxf(fmaf(h.w, s4.w, t4.w), 0.f);
        float hs[4] = {h.x, h.y, h.z, h.w};
        #pragma unroll
        for (int j = 0; j < 4; j++) {
            int d = p * 32 + dq * 4 + j;
            #pragma unroll
            for (int q = 0; q < 4; q++)
                yy[q] = f4fma(hs[j], W1s[d * 4 + ((q + p) & 3)], yy[q]);
        }
    }
    #pragma unroll
    for (int q = 0; q < 4; q++) {
        yy[q].x += __shfl_xor(yy[q].x, 1); yy[q].y += __shfl_xor(yy[q].y, 1);
        yy[q].z += __shfl_xor(yy[q].z, 1); yy[q].w += __shfl_xor(yy[q].w, 1);
        yy[q].x += __shfl_xor(yy[q].x, 2); yy[q].y += __shfl_xor(yy[q].y, 2);
        yy[q].z += __shfl_xor(yy[q].z, 2); yy[q].w += __shfl_xor(yy[q].w, 2);
    }
    ((float4*)Y)[(size_t)node * 4 + p] = yy[p];
}

// ---- out = U @ W + bias (N x 16)@(16 x 40); 4 threads/node, 10 cols each ----
__launch_bounds__(256)
__global__ void gemm_hc_reg(const float* __restrict__ U, const float* __restrict__ W,
                            const float* __restrict__ bias, float* __restrict__ out) {
    __shared__ float2 Ws[HH * 20];
    __shared__ float2 Bs[20];
    int t = threadIdx.x;
    for (int i = t; i < HH * 20; i += 256) Ws[i] = ((const float2*)W)[i];
    if (t < 20) Bs[t] = ((const float2*)bias)[t];
    __syncthreads();
    int node = blockIdx.x * 64 + (t >> 2);
    int p = t & 3;
    if (node >= NN) return;
    float u[16];
    {
        const float4* up = (const float4*)(U + (size_t)node * HH);
        float4 a = up[0], b = up[1], c = up[2], d = up[3];
        u[0]=a.x; u[1]=a.y; u[2]=a.z; u[3]=a.w; u[4]=b.x; u[5]=b.y; u[6]=b.z; u[7]=b.w;
        u[8]=c.x; u[9]=c.y; u[10]=c.z; u[11]=c.w; u[12]=d.x; u[13]=d.y; u[14]=d.z; u[15]=d.w;
    }
    float2 acc[5];
    #pragma unroll
    for (int i = 0; i < 5; i++) acc[i] = Bs[p * 5 + i];
    #pragma unroll
    for (int k = 0; k < 16; k++) {
        float uk = u[k];
        #pragma unroll
        for (int i = 0; i < 5; i++) {
            float2 w = Ws[k * 20 + p * 5 + i];
            acc[i].x = fmaf(uk, w.x, acc[i].x);
            acc[i].y = fmaf(uk, w.y, acc[i].y);
        }
    }
    float2* O = (float2*)(out + (size_t)node * CC) + p * 5;
    #pragma unroll
    for (int i = 0; i < 5; i++) O[i] = acc[i];
}

extern "C" void kernel_launch(void* const* d_in, const int* in_sizes, int n_in,
                              void* d_out, int out_size, void* d_ws, size_t ws_size,
                              hipStream_t stream) {
    const float* x     = (const float*)d_in[0];
    const float* vals  = (const float*)d_in[1];
    const float* W1    = (const float*)d_in[2];
    const float* b1    = (const float*)d_in[3];
    const float* W2    = (const float*)d_in[4];
    const float* b2    = (const float*)d_in[5];
    const float* gamma = (const float*)d_in[6];
    const float* beta  = (const float*)d_in[7];
    const float* W1f   = (const float*)d_in[8];
    const float* b1f   = (const float*)d_in[9];
    const float* W2f   = (const float*)d_in[10];
    const float* b2f   = (const float*)d_in[11];
    const int*   row   = (const int*)d_in[12];
    const int*   col   = (const int*)d_in[13];
    float* out = (float*)d_out;

    char* ws = (char*)d_ws;
    size_t off = 0;
    auto alloc = [&](size_t bytes) -> char* {
        char* p = ws + off;
        off += (bytes + 255) / 256 * 256;
        return p;
    };
    int*   rp = (int*)  alloc((NN + 1) * sizeof(int));
    float* GS = (float*)alloc(LL * 272 * sizeof(float));
    float* Y  = (float*)alloc((size_t)NN * HH * sizeof(float));
    float* T  = (float*)alloc((size_t)NN * HH * sizeof(float));
    float* U  = (float*)alloc((size_t)NN * HH * sizeof(float));

    build_rowptr<<<(NN + 256) / 256, 256, 0, stream>>>(row, rp);
    zero_buf<<<(LL * 272 + 255) / 256, 256, 0, stream>>>(GS, LL * 272);

    gemm_dh_reg<<<(NN + 63) / 64, 256, 0, stream>>>(x, W1, Y);
    for (int l = 0; l < LL; l++) {
        spmm16<true, true><<<(NN + 15) / 16, 256, 0, stream>>>(rp, col, vals, Y, b1 + l * HH, T);
        spmm16<false, false><<<(NN + 15) / 16, 256, 0, stream>>>(rp, col, vals, T, nullptr, U);
        stats_gram<<<512, 256, 0, stream>>>(U, GS + l * 272);
        const float* W1next = (l < LL - 1) ? (W1 + (l + 1) * DD * HH) : W1f;
        fused_mid<<<(NN + 63) / 64, 256, 0, stream>>>(U, GS + l * 272,
            W2 + l * HH * DD, b2 + l * DD, gamma + l * DD, beta + l * DD, W1next, Y);
    }
    spmm16<true, true><<<(NN + 15) / 16, 256, 0, stream>>>(rp, col, vals, Y, b1f, T);
    spmm16<false, false><<<(NN + 15) / 16, 256, 0, stream>>>(rp, col, vals, T, nullptr, U);
    gemm_hc_reg<<<(NN + 63) / 64, 256, 0, stream>>>(U, W2f, b2f, out);
}

// Round 5
// 574.479 us; speedup vs baseline: 1.0522x; 1.0522x over previous
//
#include <hip/hip_runtime.h>

#define NN 100000
#define NE 1600000
#define DD 128
#define HH 16
#define CC 40
#define LL 3

__device__ __forceinline__ float4 f4fma(float s, float4 w, float4 a) {
    a.x = fmaf(s, w.x, a.x); a.y = fmaf(s, w.y, a.y);
    a.z = fmaf(s, w.z, a.z); a.w = fmaf(s, w.w, a.w);
    return a;
}

// perm for [*][32]-float4 LDS arrays read at dw = p*4+dqi by 8 lanes p=0..7:
// transpose 8x4 -> 4x8 so lane p hits float4 slot (p + 8*dqi): banks 4p, disjoint.
__device__ __forceinline__ int permW2(int dw) {
    return (dw >> 2) | ((dw & 3) << 3);
}

__global__ void build_rowptr(const int* __restrict__ row, int* __restrict__ rp) {
    int i = blockIdx.x * blockDim.x + threadIdx.x;
    if (i > NN) return;
    int lo = 0, hi = NE;
    while (lo < hi) { int m = (lo + hi) >> 1; if (row[m] < i) lo = m + 1; else hi = m; }
    rp[i] = lo;
}

__global__ void zero_buf(float* __restrict__ s, int n) {
    int i = blockIdx.x * 256 + threadIdx.x;
    if (i < n) s[i] = 0.f;
}

// ---- Y = X @ W  (N x 128)@(128 x 16); 8 threads/node x 4 nodes/thread ----
__launch_bounds__(256)
__global__ void gemm_dh_reg(const float* __restrict__ X, const float* __restrict__ W,
                            float* __restrict__ Y) {
    __shared__ float4 W1s[DD * 4];   // (d,q) at d*4 + ((q + (d>>4)) & 3)
    int t = threadIdx.x;
    for (int i = t; i < DD * 4; i += 256) {
        int d = i >> 2, q = i & 3;
        W1s[d * 4 + ((q + (d >> 4)) & 3)] = ((const float4*)W)[i];
    }
    __syncthreads();
    int g = t >> 3, p = t & 7;
    int base = blockIdx.x * 128;
    int n[4]; bool v[4];
    #pragma unroll
    for (int i = 0; i < 4; i++) { n[i] = base + i * 32 + g; v[i] = n[i] < NN; }
    const float4* X4 = (const float4*)X;
    float4 y[4][4];
    #pragma unroll
    for (int i = 0; i < 4; i++)
        #pragma unroll
        for (int q = 0; q < 4; q++) y[i][q] = {0, 0, 0, 0};
    #pragma unroll
    for (int dqi = 0; dqi < 4; dqi++) {
        int dq = (p << 2) + dqi;
        float4 xv[4];
        #pragma unroll
        for (int i = 0; i < 4; i++)
            xv[i] = v[i] ? X4[(size_t)n[i] * 32 + dq] : (float4){0, 0, 0, 0};
        #pragma unroll
        for (int j = 0; j < 4; j++) {
            int d = (dq << 2) + j;
            float4 w0 = W1s[d * 4 + ((0 + p) & 3)];
            float4 w1 = W1s[d * 4 + ((1 + p) & 3)];
            float4 w2 = W1s[d * 4 + ((2 + p) & 3)];
            float4 w3 = W1s[d * 4 + ((3 + p) & 3)];
            float xs0 = j == 0 ? xv[0].x : j == 1 ? xv[0].y : j == 2 ? xv[0].z : xv[0].w;
            float xs1 = j == 0 ? xv[1].x : j == 1 ? xv[1].y : j == 2 ? xv[1].z : xv[1].w;
            float xs2 = j == 0 ? xv[2].x : j == 1 ? xv[2].y : j == 2 ? xv[2].z : xv[2].w;
            float xs3 = j == 0 ? xv[3].x : j == 1 ? xv[3].y : j == 2 ? xv[3].z : xv[3].w;
            y[0][0] = f4fma(xs0, w0, y[0][0]); y[0][1] = f4fma(xs0, w1, y[0][1]);
            y[0][2] = f4fma(xs0, w2, y[0][2]); y[0][3] = f4fma(xs0, w3, y[0][3]);
            y[1][0] = f4fma(xs1, w0, y[1][0]); y[1][1] = f4fma(xs1, w1, y[1][1]);
            y[1][2] = f4fma(xs1, w2, y[1][2]); y[1][3] = f4fma(xs1, w3, y[1][3]);
            y[2][0] = f4fma(xs2, w0, y[2][0]); y[2][1] = f4fma(xs2, w1, y[2][1]);
            y[2][2] = f4fma(xs2, w2, y[2][2]); y[2][3] = f4fma(xs2, w3, y[2][3]);
            y[3][0] = f4fma(xs3, w0, y[3][0]); y[3][1] = f4fma(xs3, w1, y[3][1]);
            y[3][2] = f4fma(xs3, w2, y[3][2]); y[3][3] = f4fma(xs3, w3, y[3][3]);
        }
    }
    #pragma unroll
    for (int i = 0; i < 4; i++)
        #pragma unroll
        for (int q = 0; q < 4; q++) {
            float4& a = y[i][q];
            a.x += __shfl_xor(a.x, 1); a.y += __shfl_xor(a.y, 1);
            a.z += __shfl_xor(a.z, 1); a.w += __shfl_xor(a.w, 1);
            a.x += __shfl_xor(a.x, 2); a.y += __shfl_xor(a.y, 2);
            a.z += __shfl_xor(a.z, 2); a.w += __shfl_xor(a.w, 2);
            a.x += __shfl_xor(a.x, 4); a.y += __shfl_xor(a.y, 4);
            a.z += __shfl_xor(a.z, 4); a.w += __shfl_xor(a.w, 4);
        }
    int wi = p >> 1, q0 = (p & 1) * 2;
    if (v[wi]) {
        ((float4*)Y)[(size_t)n[wi] * 4 + q0]     = y[wi][q0];
        ((float4*)Y)[(size_t)n[wi] * 4 + q0 + 1] = y[wi][q0 + 1];
    }
}

// ---- out[n][0:16] = sum_e vals[e]*hin[col[e]][0:16]; 4 lanes/node (R3 form) ----
template <bool RELU, bool BIAS>
__launch_bounds__(256)
__global__ void spmm16(const int* __restrict__ rp, const int* __restrict__ col,
                       const float* __restrict__ vals, const float* __restrict__ hin,
                       const float* __restrict__ bias, float* __restrict__ out) {
    int node = blockIdx.x * 64 + (threadIdx.x >> 2);
    int f = threadIdx.x & 3;
    if (node >= NN) return;
    int s = rp[node], e = rp[node + 1];
    const float4* h4 = (const float4*)hin;
    float ax = 0.f, ay = 0.f, az = 0.f, aw = 0.f;
    int j = s;
    for (; j + 3 < e; j += 4) {
        int c0 = col[j], c1 = col[j + 1], c2 = col[j + 2], c3 = col[j + 3];
        float v0 = vals[j], v1 = vals[j + 1], v2 = vals[j + 2], v3 = vals[j + 3];
        float4 a0 = h4[c0 * 4 + f];
        float4 a1 = h4[c1 * 4 + f];
        float4 a2 = h4[c2 * 4 + f];
        float4 a3 = h4[c3 * 4 + f];
        ax = fmaf(v0, a0.x, ax); ay = fmaf(v0, a0.y, ay); az = fmaf(v0, a0.z, az); aw = fmaf(v0, a0.w, aw);
        ax = fmaf(v1, a1.x, ax); ay = fmaf(v1, a1.y, ay); az = fmaf(v1, a1.z, az); aw = fmaf(v1, a1.w, aw);
        ax = fmaf(v2, a2.x, ax); ay = fmaf(v2, a2.y, ay); az = fmaf(v2, a2.z, az); aw = fmaf(v2, a2.w, aw);
        ax = fmaf(v3, a3.x, ax); ay = fmaf(v3, a3.y, ay); az = fmaf(v3, a3.z, az); aw = fmaf(v3, a3.w, aw);
    }
    for (; j < e; j++) {
        int c = col[j]; float v = vals[j];
        float4 a = h4[c * 4 + f];
        ax = fmaf(v, a.x, ax); ay = fmaf(v, a.y, ay); az = fmaf(v, a.z, az); aw = fmaf(v, a.w, aw);
    }
    if (BIAS) {
        float4 b = ((const float4*)bias)[f];
        ax += b.x; ay += b.y; az += b.z; aw += b.w;
    }
    if (RELU) {
        ax = fmaxf(ax, 0.f); ay = fmaxf(ay, 0.f); az = fmaxf(az, 0.f); aw = fmaxf(aw, 0.f);
    }
    float4 o = {ax, ay, az, aw};
    ((float4*)out)[(size_t)node * 4 + f] = o;
}

// GS[0..255] = G = U^T U, GS[256..271] = colsum(U)
__launch_bounds__(256)
__global__ void stats_gram(const float* __restrict__ U, float* __restrict__ GS) {
    __shared__ float Us[64 * 20];
    int t = threadIdx.x;
    int k = t & 15, kp = t >> 4;
    float g = 0.f, s = 0.f;
    const int npb = (NN + gridDim.x - 1) / gridDim.x;
    int n0 = blockIdx.x * npb;
    int n1 = min(n0 + npb, NN);
    for (int nb = n0; nb < n1; nb += 64) {
        int cnt = min(64, n1 - nb);
        __syncthreads();
        for (int i = t; i < cnt * 4; i += 256) {
            int r = i >> 2, qq = i & 3;
            ((float4*)&Us[r * 20])[qq] = ((const float4*)(U + (size_t)(nb + r) * HH))[qq];
        }
        __syncthreads();
        for (int n = 0; n < cnt; n++) {
            float a = Us[n * 20 + k];
            float b = Us[n * 20 + kp];
            g = fmaf(a, b, g);
            s += a;
        }
    }
    atomicAdd(&GS[kp * 16 + k], g);
    if (kp == 0) atomicAdd(&GS[256 + k], s);
}

// ---- Y = relu(BN(U@W2 + b2)) @ W1n ; 8 threads/node x 4 nodes/thread ----
__launch_bounds__(256)
__global__ void fused_mid(const float* __restrict__ U, const float* __restrict__ GS,
                          const float* __restrict__ W2, const float* __restrict__ b2,
                          const float* __restrict__ gamma, const float* __restrict__ beta,
                          const float* __restrict__ W1n, float* __restrict__ Y) {
    __shared__ float4 W2s[HH * 32];      // (k,dw) at k*32 + permW2(dw)
    __shared__ float4 W1s[DD * 4];       // (d,q)  at d*4 + ((q + (d>>4)) & 3)
    __shared__ float4 SC4[32], SH4[32];  // permW2 layout
    __shared__ float  Gs[272];
    int t = threadIdx.x;
    for (int i = t; i < HH * 32; i += 256) {
        int k = i >> 5, dw = i & 31;
        W2s[k * 32 + permW2(dw)] = ((const float4*)W2)[i];
    }
    for (int i = t; i < DD * 4; i += 256) {
        int d = i >> 2, q = i & 3;
        W1s[d * 4 + ((q + (d >> 4)) & 3)] = ((const float4*)W1n)[i];
    }
    for (int i = t; i < 272; i += 256) Gs[i] = GS[i];
    __syncthreads();
    if (t < DD) {
        int d = t;
        float w[16];
        #pragma unroll
        for (int k = 0; k < 16; k++) w[k] = W2[k * DD + d];
        float sdot = 0.f, quad = 0.f;
        #pragma unroll
        for (int k = 0; k < 16; k++) {
            sdot = fmaf(Gs[256 + k], w[k], sdot);
            float vk = 0.f;
            #pragma unroll
            for (int kp = 0; kp < 16; kp++) vk = fmaf(Gs[k * 16 + kp], w[kp], vk);
            quad = fmaf(w[k], vk, quad);
        }
        float b = b2[d];
        float sumH  = sdot + (float)NN * b;
        float sumsq = quad + 2.f * b * sdot + (float)NN * b * b;
        float mean = sumH * (1.f / NN);
        float var  = sumsq * (1.f / NN) - mean * mean;
        float inv  = rsqrtf(var + 1e-5f);
        float gm = gamma[d] * inv;
        int loc = permW2(d >> 2), jj = d & 3;
        ((float*)&SC4[loc])[jj] = gm;
        ((float*)&SH4[loc])[jj] = (b - mean) * gm + beta[d];
    }
    __syncthreads();
    int g = t >> 3, p = t & 7;
    int base = blockIdx.x * 128;
    int n[4]; bool v[4];
    #pragma unroll
    for (int i = 0; i < 4; i++) { n[i] = base + i * 32 + g; v[i] = n[i] < NN; }
    float u[4][16];
    #pragma unroll
    for (int i = 0; i < 4; i++) {
        if (v[i]) {
            const float4* up = (const float4*)(U + (size_t)n[i] * HH);
            float4 a = up[0], b = up[1], c = up[2], d = up[3];
            u[i][0]=a.x; u[i][1]=a.y; u[i][2]=a.z; u[i][3]=a.w;
            u[i][4]=b.x; u[i][5]=b.y; u[i][6]=b.z; u[i][7]=b.w;
            u[i][8]=c.x; u[i][9]=c.y; u[i][10]=c.z; u[i][11]=c.w;
            u[i][12]=d.x; u[i][13]=d.y; u[i][14]=d.z; u[i][15]=d.w;
        } else {
            #pragma unroll
            for (int k = 0; k < 16; k++) u[i][k] = 0.f;
        }
    }
    float4 y[4][4];
    #pragma unroll
    for (int i = 0; i < 4; i++)
        #pragma unroll
        for (int q = 0; q < 4; q++) y[i][q] = {0, 0, 0, 0};
    #pragma unroll
    for (int dqi = 0; dqi < 4; dqi++) {
        int rpos = p + (dqi << 3);        // permW2(p*4+dqi)
        float4 h[4];
        #pragma unroll
        for (int i = 0; i < 4; i++) h[i] = {0, 0, 0, 0};
        #pragma unroll
        for (int k = 0; k < 16; k++) {
            float4 w = W2s[k * 32 + rpos];
            h[0] = f4fma(u[0][k], w, h[0]);
            h[1] = f4fma(u[1][k], w, h[1]);
            h[2] = f4fma(u[2][k], w, h[2]);
            h[3] = f4fma(u[3][k], w, h[3]);
        }
        float4 s4 = SC4[rpos], t4 = SH4[rpos];
        #pragma unroll
        for (int i = 0; i < 4; i++) {
            h[i].x = fmaxf(fmaf(h[i].x, s4.x, t4.x), 0.f);
            h[i].y = fmaxf(fmaf(h[i].y, s4.y, t4.y), 0.f);
            h[i].z = fmaxf(fmaf(h[i].z, s4.z, t4.z), 0.f);
            h[i].w = fmaxf(fmaf(h[i].w, s4.w, t4.w), 0.f);
        }
        int dq = (p << 2) + dqi;
        #pragma unroll
        for (int j = 0; j < 4; j++) {
            int d = (dq << 2) + j;
            float4 w0 = W1s[d * 4 + ((0 + p) & 3)];
            float4 w1 = W1s[d * 4 + ((1 + p) & 3)];
            float4 w2 = W1s[d * 4 + ((2 + p) & 3)];
            float4 w3 = W1s[d * 4 + ((3 + p) & 3)];
            float h0 = j == 0 ? h[0].x : j == 1 ? h[0].y : j == 2 ? h[0].z : h[0].w;
            float h1 = j == 0 ? h[1].x : j == 1 ? h[1].y : j == 2 ? h[1].z : h[1].w;
            float h2 = j == 0 ? h[2].x : j == 1 ? h[2].y : j == 2 ? h[2].z : h[2].w;
            float h3 = j == 0 ? h[3].x : j == 1 ? h[3].y : j == 2 ? h[3].z : h[3].w;
            y[0][0] = f4fma(h0, w0, y[0][0]); y[0][1] = f4fma(h0, w1, y[0][1]);
            y[0][2] = f4fma(h0, w2, y[0][2]); y[0][3] = f4fma(h0, w3, y[0][3]);
            y[1][0] = f4fma(h1, w0, y[1][0]); y[1][1] = f4fma(h1, w1, y[1][1]);
            y[1][2] = f4fma(h1, w2, y[1][2]); y[1][3] = f4fma(h1, w3, y[1][3]);
            y[2][0] = f4fma(h2, w0, y[2][0]); y[2][1] = f4fma(h2, w1, y[2][1]);
            y[2][2] = f4fma(h2, w2, y[2][2]); y[2][3] = f4fma(h2, w3, y[2][3]);
            y[3][0] = f4fma(h3, w0, y[3][0]); y[3][1] = f4fma(h3, w1, y[3][1]);
            y[3][2] = f4fma(h3, w2, y[3][2]); y[3][3] = f4fma(h3, w3, y[3][3]);
        }
    }
    #pragma unroll
    for (int i = 0; i < 4; i++)
        #pragma unroll
        for (int q = 0; q < 4; q++) {
            float4& a = y[i][q];
            a.x += __shfl_xor(a.x, 1); a.y += __shfl_xor(a.y, 1);
            a.z += __shfl_xor(a.z, 1); a.w += __shfl_xor(a.w, 1);
            a.x += __shfl_xor(a.x, 2); a.y += __shfl_xor(a.y, 2);
            a.z += __shfl_xor(a.z, 2); a.w += __shfl_xor(a.w, 2);
            a.x += __shfl_xor(a.x, 4); a.y += __shfl_xor(a.y, 4);
            a.z += __shfl_xor(a.z, 4); a.w += __shfl_xor(a.w, 4);
        }
    int wi = p >> 1, q0 = (p & 1) * 2;
    if (v[wi]) {
        ((float4*)Y)[(size_t)n[wi] * 4 + q0]     = y[wi][q0];
        ((float4*)Y)[(size_t)n[wi] * 4 + q0 + 1] = y[wi][q0 + 1];
    }
}

// ---- out = U @ W + bias (N x 16)@(16 x 40); 4 threads/node, 10 cols each ----
__launch_bounds__(256)
__global__ void gemm_hc_reg(const float* __restrict__ U, const float* __restrict__ W,
                            const float* __restrict__ bias, float* __restrict__ out) {
    __shared__ float2 Ws[HH * 20];
    __shared__ float2 Bs[20];
    int t = threadIdx.x;
    for (int i = t; i < HH * 20; i += 256) Ws[i] = ((const float2*)W)[i];
    if (t < 20) Bs[t] = ((const float2*)bias)[t];
    __syncthreads();
    int node = blockIdx.x * 64 + (t >> 2);
    int p = t & 3;
    if (node >= NN) return;
    float u[16];
    {
        const float4* up = (const float4*)(U + (size_t)node * HH);
        float4 a = up[0], b = up[1], c = up[2], d = up[3];
        u[0]=a.x; u[1]=a.y; u[2]=a.z; u[3]=a.w; u[4]=b.x; u[5]=b.y; u[6]=b.z; u[7]=b.w;
        u[8]=c.x; u[9]=c.y; u[10]=c.z; u[11]=c.w; u[12]=d.x; u[13]=d.y; u[14]=d.z; u[15]=d.w;
    }
    float2 acc[5];
    #pragma unroll
    for (int i = 0; i < 5; i++) acc[i] = Bs[p * 5 + i];
    #pragma unroll
    for (int k = 0; k < 16; k++) {
        float uk = u[k];
        #pragma unroll
        for (int i = 0; i < 5; i++) {
            float2 w = Ws[k * 20 + p * 5 + i];
            acc[i].x = fmaf(uk, w.x, acc[i].x);
            acc[i].y = fmaf(uk, w.y, acc[i].y);
        }
    }
    float2* O = (float2*)(out + (size_t)node * CC) + p * 5;
    #pragma unroll
    for (int i = 0; i < 5; i++) O[i] = acc[i];
}

extern "C" void kernel_launch(void* const* d_in, const int* in_sizes, int n_in,
                              void* d_out, int out_size, void* d_ws, size_t ws_size,
                              hipStream_t stream) {
    const float* x     = (const float*)d_in[0];
    const float* vals  = (const float*)d_in[1];
    const float* W1    = (const float*)d_in[2];
    const float* b1    = (const float*)d_in[3];
    const float* W2    = (const float*)d_in[4];
    const float* b2    = (const float*)d_in[5];
    const float* gamma = (const float*)d_in[6];
    const float* beta  = (const float*)d_in[7];
    const float* W1f   = (const float*)d_in[8];
    const float* b1f   = (const float*)d_in[9];
    const float* W2f   = (const float*)d_in[10];
    const float* b2f   = (const float*)d_in[11];
    const int*   row   = (const int*)d_in[12];
    const int*   col   = (const int*)d_in[13];
    float* out = (float*)d_out;

    char* ws = (char*)d_ws;
    size_t off = 0;
    auto alloc = [&](size_t bytes) -> char* {
        char* p = ws + off;
        off += (bytes + 255) / 256 * 256;
        return p;
    };
    int*   rp = (int*)  alloc((NN + 1) * sizeof(int));
    float* GS = (float*)alloc(LL * 272 * sizeof(float));
    float* Y  = (float*)alloc((size_t)NN * HH * sizeof(float));
    float* T  = (float*)alloc((size_t)NN * HH * sizeof(float));
    float* U  = (float*)alloc((size_t)NN * HH * sizeof(float));

    build_rowptr<<<(NN + 256) / 256, 256, 0, stream>>>(row, rp);
    zero_buf<<<(LL * 272 + 255) / 256, 256, 0, stream>>>(GS, LL * 272);

    gemm_dh_reg<<<(NN + 127) / 128, 256, 0, stream>>>(x, W1, Y);
    for (int l = 0; l < LL; l++) {
        spmm16<true, true><<<(NN + 63) / 64, 256, 0, stream>>>(rp, col, vals, Y, b1 + l * HH, T);
        spmm16<false, false><<<(NN + 63) / 64, 256, 0, stream>>>(rp, col, vals, T, nullptr, U);
        stats_gram<<<512, 256, 0, stream>>>(U, GS + l * 272);
        const float* W1next = (l < LL - 1) ? (W1 + (l + 1) * DD * HH) : W1f;
        fused_mid<<<(NN + 127) / 128, 256, 0, stream>>>(U, GS + l * 272,
            W2 + l * HH * DD, b2 + l * DD, gamma + l * DD, beta + l * DD, W1next, Y);
    }
    spmm16<true, true><<<(NN + 63) / 64, 256, 0, stream>>>(rp, col, vals, Y, b1f, T);
    spmm16<false, false><<<(NN + 63) / 64, 256, 0, stream>>>(rp, col, vals, T, nullptr, U);
    gemm_hc_reg<<<(NN + 63) / 64, 256, 0, stream>>>(U, W2f, b2f, out);
}

// Round 6
// 527.441 us; speedup vs baseline: 1.1460x; 1.0892x over previous
//
#include <hip/hip_runtime.h>

#define NN 100000
#define NE 1600000
#define DD 128
#define HH 16
#define CC 40
#define LL 3

__device__ __forceinline__ float4 f4fma(float s, float4 w, float4 a) {
    a.x = fmaf(s, w.x, a.x); a.y = fmaf(s, w.y, a.y);
    a.z = fmaf(s, w.z, a.z); a.w = fmaf(s, w.w, a.w);
    return a;
}

// perm for [*][32]-float4 LDS arrays read at dw = p*4+dqi by 8 lanes p=0..7:
// transpose 8x4 -> 4x8 so lane p hits float4 slot (p + 8*dqi): banks 4p, disjoint.
__device__ __forceinline__ int permW2(int dw) {
    return (dw >> 2) | ((dw & 3) << 3);
}

// Edge-centric rowptr: rp[i] = first edge e with row[e] >= i (row sorted).
__global__ void build_rowptr(const int* __restrict__ row, int* __restrict__ rp) {
    int e = blockIdx.x * 256 + threadIdx.x;
    if (e >= NE) return;
    int r1 = row[e];
    int r0 = (e == 0) ? -1 : row[e - 1];
    for (int i = r0 + 1; i <= r1; i++) rp[i] = e;
    if (e == NE - 1) {
        for (int i = r1 + 1; i <= NN; i++) rp[i] = NE;
    }
}

__global__ void zero_buf(float* __restrict__ s, int n) {
    int i = blockIdx.x * 256 + threadIdx.x;
    if (i < n) s[i] = 0.f;
}

// ---- Y = X @ W  (N x 128)@(128 x 16); thread-per-node, broadcast W reads ----
__launch_bounds__(256)
__global__ void gemm_dh_reg(const float* __restrict__ X, const float* __restrict__ W,
                            float* __restrict__ Y) {
    __shared__ float4 Ws[DD * 4];   // W[d][h] as float4 over h
    int t = threadIdx.x;
    for (int i = t; i < DD * 4; i += 256) Ws[i] = ((const float4*)W)[i];
    __syncthreads();
    int n = blockIdx.x * 256 + t;
    if (n >= NN) return;
    const float4* X4 = (const float4*)(X + (size_t)n * DD);
    float4 y0 = {0,0,0,0}, y1 = {0,0,0,0}, y2 = {0,0,0,0}, y3 = {0,0,0,0};
    #pragma unroll 8
    for (int dc = 0; dc < 32; dc++) {
        float4 xv = X4[dc];
        float xs[4] = {xv.x, xv.y, xv.z, xv.w};
        #pragma unroll
        for (int j = 0; j < 4; j++) {
            int d = dc * 4 + j;
            float xj = xs[j];
            y0 = f4fma(xj, Ws[d * 4 + 0], y0);
            y1 = f4fma(xj, Ws[d * 4 + 1], y1);
            y2 = f4fma(xj, Ws[d * 4 + 2], y2);
            y3 = f4fma(xj, Ws[d * 4 + 3], y3);
        }
    }
    float4* Yp = (float4*)(Y + (size_t)n * HH);
    Yp[0] = y0; Yp[1] = y1; Yp[2] = y2; Yp[3] = y3;
}

// ---- out[n][0:16] = sum_e vals[e]*hin[col[e]][0:16]; 4 lanes/node,
//      aligned int4/float4 edge loads, 4 outstanding gathers ----
template <bool RELU, bool BIAS>
__launch_bounds__(256)
__global__ void spmm16(const int* __restrict__ rp, const int* __restrict__ col,
                       const float* __restrict__ vals, const float* __restrict__ hin,
                       const float* __restrict__ bias, float* __restrict__ out) {
    int node = blockIdx.x * 64 + (threadIdx.x >> 2);
    int f = threadIdx.x & 3;
    if (node >= NN) return;
    int s = rp[node], e = rp[node + 1];
    const float4* h4 = (const float4*)hin;
    float4 acc = {0, 0, 0, 0};
    int j = s;
    int sa = (s + 3) & ~3;           // align to 16B for vector edge loads
    int pe = min(sa, e);
    for (; j < pe; j++)
        acc = f4fma(vals[j], h4[(size_t)col[j] * 4 + f], acc);
    for (; j + 3 < e; j += 4) {
        int4   c4 = *(const int4*)(col + j);
        float4 v4 = *(const float4*)(vals + j);
        float4 a0 = h4[(size_t)c4.x * 4 + f];
        float4 a1 = h4[(size_t)c4.y * 4 + f];
        float4 a2 = h4[(size_t)c4.z * 4 + f];
        float4 a3 = h4[(size_t)c4.w * 4 + f];
        acc = f4fma(v4.x, a0, acc);
        acc = f4fma(v4.y, a1, acc);
        acc = f4fma(v4.z, a2, acc);
        acc = f4fma(v4.w, a3, acc);
    }
    for (; j < e; j++)
        acc = f4fma(vals[j], h4[(size_t)col[j] * 4 + f], acc);
    if (BIAS) {
        float4 b = ((const float4*)bias)[f];
        acc.x += b.x; acc.y += b.y; acc.z += b.z; acc.w += b.w;
    }
    if (RELU) {
        acc.x = fmaxf(acc.x, 0.f); acc.y = fmaxf(acc.y, 0.f);
        acc.z = fmaxf(acc.z, 0.f); acc.w = fmaxf(acc.w, 0.f);
    }
    ((float4*)out)[(size_t)node * 4 + f] = acc;
}

// GS[0..255] = G = U^T U, GS[256..271] = colsum(U)
__launch_bounds__(256)
__global__ void stats_gram(const float* __restrict__ U, float* __restrict__ GS) {
    __shared__ float Us[64 * 20];
    int t = threadIdx.x;
    int k = t & 15, kp = t >> 4;
    float g = 0.f, s = 0.f;
    const int npb = (NN + gridDim.x - 1) / gridDim.x;
    int n0 = blockIdx.x * npb;
    int n1 = min(n0 + npb, NN);
    for (int nb = n0; nb < n1; nb += 64) {
        int cnt = min(64, n1 - nb);
        __syncthreads();
        for (int i = t; i < cnt * 4; i += 256) {
            int r = i >> 2, qq = i & 3;
            ((float4*)&Us[r * 20])[qq] = ((const float4*)(U + (size_t)(nb + r) * HH))[qq];
        }
        __syncthreads();
        for (int n = 0; n < cnt; n++) {
            float a = Us[n * 20 + k];
            float b = Us[n * 20 + kp];
            g = fmaf(a, b, g);
            s += a;
        }
    }
    atomicAdd(&GS[kp * 16 + k], g);
    if (kp == 0) atomicAdd(&GS[256 + k], s);
}

// ---- Y = relu(BN(U@W2 + b2)) @ W1n ; 8 threads/node x 4 nodes/thread ----
__launch_bounds__(256)
__global__ void fused_mid(const float* __restrict__ U, const float* __restrict__ GS,
                          const float* __restrict__ W2, const float* __restrict__ b2,
                          const float* __restrict__ gamma, const float* __restrict__ beta,
                          const float* __restrict__ W1n, float* __restrict__ Y) {
    __shared__ float4 W2s[HH * 32];      // (k,dw) at k*32 + permW2(dw)
    __shared__ float4 W1s[DD * 4];       // (d,q)  at d*4 + ((q + (d>>4)) & 3)
    __shared__ float4 SC4[32], SH4[32];  // permW2 layout
    __shared__ float  Gs[272];
    int t = threadIdx.x;
    for (int i = t; i < HH * 32; i += 256) {
        int k = i >> 5, dw = i & 31;
        W2s[k * 32 + permW2(dw)] = ((const float4*)W2)[i];
    }
    for (int i = t; i < DD * 4; i += 256) {
        int d = i >> 2, q = i & 3;
        W1s[d * 4 + ((q + (d >> 4)) & 3)] = ((const float4*)W1n)[i];
    }
    for (int i = t; i < 272; i += 256) Gs[i] = GS[i];
    __syncthreads();
    if (t < DD) {
        int d = t;
        float w[16];
        #pragma unroll
        for (int k = 0; k < 16; k++) w[k] = W2[k * DD + d];
        float sdot = 0.f, quad = 0.f;
        #pragma unroll
        for (int k = 0; k < 16; k++) {
            sdot = fmaf(Gs[256 + k], w[k], sdot);
            float vk = 0.f;
            #pragma unroll
            for (int kp = 0; kp < 16; kp++) vk = fmaf(Gs[k * 16 + kp], w[kp], vk);
            quad = fmaf(w[k], vk, quad);
        }
        float b = b2[d];
        float sumH  = sdot + (float)NN * b;
        float sumsq = quad + 2.f * b * sdot + (float)NN * b * b;
        float mean = sumH * (1.f / NN);
        float var  = sumsq * (1.f / NN) - mean * mean;
        float inv  = rsqrtf(var + 1e-5f);
        float gm = gamma[d] * inv;
        int loc = permW2(d >> 2), jj = d & 3;
        ((float*)&SC4[loc])[jj] = gm;
        ((float*)&SH4[loc])[jj] = (b - mean) * gm + beta[d];
    }
    __syncthreads();
    int g = t >> 3, p = t & 7;
    int base = blockIdx.x * 128;
    int n[4]; bool v[4];
    #pragma unroll
    for (int i = 0; i < 4; i++) { n[i] = base + i * 32 + g; v[i] = n[i] < NN; }
    float u[4][16];
    #pragma unroll
    for (int i = 0; i < 4; i++) {
        if (v[i]) {
            const float4* up = (const float4*)(U + (size_t)n[i] * HH);
            float4 a = up[0], b = up[1], c = up[2], d = up[3];
            u[i][0]=a.x; u[i][1]=a.y; u[i][2]=a.z; u[i][3]=a.w;
            u[i][4]=b.x; u[i][5]=b.y; u[i][6]=b.z; u[i][7]=b.w;
            u[i][8]=c.x; u[i][9]=c.y; u[i][10]=c.z; u[i][11]=c.w;
            u[i][12]=d.x; u[i][13]=d.y; u[i][14]=d.z; u[i][15]=d.w;
        } else {
            #pragma unroll
            for (int k = 0; k < 16; k++) u[i][k] = 0.f;
        }
    }
    float4 y[4][4];
    #pragma unroll
    for (int i = 0; i < 4; i++)
        #pragma unroll
        for (int q = 0; q < 4; q++) y[i][q] = {0, 0, 0, 0};
    #pragma unroll
    for (int dqi = 0; dqi < 4; dqi++) {
        int rpos = p + (dqi << 3);        // permW2(p*4+dqi)
        float4 h[4];
        #pragma unroll
        for (int i = 0; i < 4; i++) h[i] = {0, 0, 0, 0};
        #pragma unroll
        for (int k = 0; k < 16; k++) {
            float4 w = W2s[k * 32 + rpos];
            h[0] = f4fma(u[0][k], w, h[0]);
            h[1] = f4fma(u[1][k], w, h[1]);
            h[2] = f4fma(u[2][k], w, h[2]);
            h[3] = f4fma(u[3][k], w, h[3]);
        }
        float4 s4 = SC4[rpos], t4 = SH4[rpos];
        #pragma unroll
        for (int i = 0; i < 4; i++) {
            h[i].x = fmaxf(fmaf(h[i].x, s4.x, t4.x), 0.f);
            h[i].y = fmaxf(fmaf(h[i].y, s4.y, t4.y), 0.f);
            h[i].z = fmaxf(fmaf(h[i].z, s4.z, t4.z), 0.f);
            h[i].w = fmaxf(fmaf(h[i].w, s4.w, t4.w), 0.f);
        }
        int dq = (p << 2) + dqi;
        #pragma unroll
        for (int j = 0; j < 4; j++) {
            int d = (dq << 2) + j;
            float4 w0 = W1s[d * 4 + ((0 + p) & 3)];
            float4 w1 = W1s[d * 4 + ((1 + p) & 3)];
            float4 w2 = W1s[d * 4 + ((2 + p) & 3)];
            float4 w3 = W1s[d * 4 + ((3 + p) & 3)];
            float h0 = j == 0 ? h[0].x : j == 1 ? h[0].y : j == 2 ? h[0].z : h[0].w;
            float h1 = j == 0 ? h[1].x : j == 1 ? h[1].y : j == 2 ? h[1].z : h[1].w;
            float h2 = j == 0 ? h[2].x : j == 1 ? h[2].y : j == 2 ? h[2].z : h[2].w;
            float h3 = j == 0 ? h[3].x : j == 1 ? h[3].y : j == 2 ? h[3].z : h[3].w;
            y[0][0] = f4fma(h0, w0, y[0][0]); y[0][1] = f4fma(h0, w1, y[0][1]);
            y[0][2] = f4fma(h0, w2, y[0][2]); y[0][3] = f4fma(h0, w3, y[0][3]);
            y[1][0] = f4fma(h1, w0, y[1][0]); y[1][1] = f4fma(h1, w1, y[1][1]);
            y[1][2] = f4fma(h1, w2, y[1][2]); y[1][3] = f4fma(h1, w3, y[1][3]);
            y[2][0] = f4fma(h2, w0, y[2][0]); y[2][1] = f4fma(h2, w1, y[2][1]);
            y[2][2] = f4fma(h2, w2, y[2][2]); y[2][3] = f4fma(h2, w3, y[2][3]);
            y[3][0] = f4fma(h3, w0, y[3][0]); y[3][1] = f4fma(h3, w1, y[3][1]);
            y[3][2] = f4fma(h3, w2, y[3][2]); y[3][3] = f4fma(h3, w3, y[3][3]);
        }
    }
    #pragma unroll
    for (int i = 0; i < 4; i++)
        #pragma unroll
        for (int q = 0; q < 4; q++) {
            float4& a = y[i][q];
            a.x += __shfl_xor(a.x, 1); a.y += __shfl_xor(a.y, 1);
            a.z += __shfl_xor(a.z, 1); a.w += __shfl_xor(a.w, 1);
            a.x += __shfl_xor(a.x, 2); a.y += __shfl_xor(a.y, 2);
            a.z += __shfl_xor(a.z, 2); a.w += __shfl_xor(a.w, 2);
            a.x += __shfl_xor(a.x, 4); a.y += __shfl_xor(a.y, 4);
            a.z += __shfl_xor(a.z, 4); a.w += __shfl_xor(a.w, 4);
        }
    int wi = p >> 1, q0 = (p & 1) * 2;
    if (v[wi]) {
        ((float4*)Y)[(size_t)n[wi] * 4 + q0]     = y[wi][q0];
        ((float4*)Y)[(size_t)n[wi] * 4 + q0 + 1] = y[wi][q0 + 1];
    }
}

// ---- out = U @ W + bias (N x 16)@(16 x 40); 4 threads/node, 10 cols each ----
__launch_bounds__(256)
__global__ void gemm_hc_reg(const float* __restrict__ U, const float* __restrict__ W,
                            const float* __restrict__ bias, float* __restrict__ out) {
    __shared__ float2 Ws[HH * 20];
    __shared__ float2 Bs[20];
    int t = threadIdx.x;
    for (int i = t; i < HH * 20; i += 256) Ws[i] = ((const float2*)W)[i];
    if (t < 20) Bs[t] = ((const float2*)bias)[t];
    __syncthreads();
    int node = blockIdx.x * 64 + (t >> 2);
    int p = t & 3;
    if (node >= NN) return;
    float u[16];
    {
        const float4* up = (const float4*)(U + (size_t)node * HH);
        float4 a = up[0], b = up[1], c = up[2], d = up[3];
        u[0]=a.x; u[1]=a.y; u[2]=a.z; u[3]=a.w; u[4]=b.x; u[5]=b.y; u[6]=b.z; u[7]=b.w;
        u[8]=c.x; u[9]=c.y; u[10]=c.z; u[11]=c.w; u[12]=d.x; u[13]=d.y; u[14]=d.z; u[15]=d.w;
    }
    float2 acc[5];
    #pragma unroll
    for (int i = 0; i < 5; i++) acc[i] = Bs[p * 5 + i];
    #pragma unroll
    for (int k = 0; k < 16; k++) {
        float uk = u[k];
        #pragma unroll
        for (int i = 0; i < 5; i++) {
            float2 w = Ws[k * 20 + p * 5 + i];
            acc[i].x = fmaf(uk, w.x, acc[i].x);
            acc[i].y = fmaf(uk, w.y, acc[i].y);
        }
    }
    float2* O = (float2*)(out + (size_t)node * CC) + p * 5;
    #pragma unroll
    for (int i = 0; i < 5; i++) O[i] = acc[i];
}

extern "C" void kernel_launch(void* const* d_in, const int* in_sizes, int n_in,
                              void* d_out, int out_size, void* d_ws, size_t ws_size,
                              hipStream_t stream) {
    const float* x     = (const float*)d_in[0];
    const float* vals  = (const float*)d_in[1];
    const float* W1    = (const float*)d_in[2];
    const float* b1    = (const float*)d_in[3];
    const float* W2    = (const float*)d_in[4];
    const float* b2    = (const float*)d_in[5];
    const float* gamma = (const float*)d_in[6];
    const float* beta  = (const float*)d_in[7];
    const float* W1f   = (const float*)d_in[8];
    const float* b1f   = (const float*)d_in[9];
    const float* W2f   = (const float*)d_in[10];
    const float* b2f   = (const float*)d_in[11];
    const int*   row   = (const int*)d_in[12];
    const int*   col   = (const int*)d_in[13];
    float* out = (float*)d_out;

    char* ws = (char*)d_ws;
    size_t off = 0;
    auto alloc = [&](size_t bytes) -> char* {
        char* p = ws + off;
        off += (bytes + 255) / 256 * 256;
        return p;
    };
    int*   rp = (int*)  alloc((NN + 1) * sizeof(int));
    float* GS = (float*)alloc(LL * 272 * sizeof(float));
    float* Y  = (float*)alloc((size_t)NN * HH * sizeof(float));
    float* T  = (float*)alloc((size_t)NN * HH * sizeof(float));
    float* U  = (float*)alloc((size_t)NN * HH * sizeof(float));

    build_rowptr<<<(NE + 255) / 256, 256, 0, stream>>>(row, rp);
    zero_buf<<<(LL * 272 + 255) / 256, 256, 0, stream>>>(GS, LL * 272);

    gemm_dh_reg<<<(NN + 255) / 256, 256, 0, stream>>>(x, W1, Y);
    for (int l = 0; l < LL; l++) {
        spmm16<true, true><<<(NN + 63) / 64, 256, 0, stream>>>(rp, col, vals, Y, b1 + l * HH, T);
        spmm16<false, false><<<(NN + 63) / 64, 256, 0, stream>>>(rp, col, vals, T, nullptr, U);
        stats_gram<<<512, 256, 0, stream>>>(U, GS + l * 272);
        const float* W1next = (l < LL - 1) ? (W1 + (l + 1) * DD * HH) : W1f;
        fused_mid<<<(NN + 127) / 128, 256, 0, stream>>>(U, GS + l * 272,
            W2 + l * HH * DD, b2 + l * DD, gamma + l * DD, beta + l * DD, W1next, Y);
    }
    spmm16<true, true><<<(NN + 63) / 64, 256, 0, stream>>>(rp, col, vals, Y, b1f, T);
    spmm16<false, false><<<(NN + 63) / 64, 256, 0, stream>>>(rp, col, vals, T, nullptr, U);
    gemm_hc_reg<<<(NN + 63) / 64, 256, 0, stream>>>(U, W2f, b2f, out);
}

// Round 7
// 527.223 us; speedup vs baseline: 1.1465x; 1.0004x over previous
//
#include <hip/hip_runtime.h>

#define NN 100000
#define NE 1600000
#define DD 128
#define HH 16
#define CC 40
#define LL 3

__device__ __forceinline__ float4 f4fma(float s, float4 w, float4 a) {
    a.x = fmaf(s, w.x, a.x); a.y = fmaf(s, w.y, a.y);
    a.z = fmaf(s, w.z, a.z); a.w = fmaf(s, w.w, a.w);
    return a;
}

// perm for [*][32]-float4 LDS arrays read at dw = p*4+dqi by 8 lanes p=0..7:
// transpose 8x4 -> 4x8 so lane p hits float4 slot (p + 8*dqi): banks 4p, disjoint.
__device__ __forceinline__ int permW2(int dw) {
    return (dw >> 2) | ((dw & 3) << 3);
}

// Edge-centric rowptr: rp[i] = first edge e with row[e] >= i (row sorted).
__global__ void build_rowptr(const int* __restrict__ row, int* __restrict__ rp) {
    int e = blockIdx.x * 256 + threadIdx.x;
    if (e >= NE) return;
    int r1 = row[e];
    int r0 = (e == 0) ? -1 : row[e - 1];
    for (int i = r0 + 1; i <= r1; i++) rp[i] = e;
    if (e == NE - 1) {
        for (int i = r1 + 1; i <= NN; i++) rp[i] = NE;
    }
}

__global__ void zero_buf(float* __restrict__ s, int n) {
    int i = blockIdx.x * 256 + threadIdx.x;
    if (i < n) s[i] = 0.f;
}

// ---- Y = X @ W  (N x 128)@(128 x 16); thread-per-node, broadcast W reads ----
__launch_bounds__(256)
__global__ void gemm_dh_reg(const float* __restrict__ X, const float* __restrict__ W,
                            float* __restrict__ Y) {
    __shared__ float4 Ws[DD * 4];   // W[d][h] as float4 over h
    int t = threadIdx.x;
    for (int i = t; i < DD * 4; i += 256) Ws[i] = ((const float4*)W)[i];
    __syncthreads();
    int n = blockIdx.x * 256 + t;
    if (n >= NN) return;
    const float4* X4 = (const float4*)(X + (size_t)n * DD);
    float4 y0 = {0,0,0,0}, y1 = {0,0,0,0}, y2 = {0,0,0,0}, y3 = {0,0,0,0};
    #pragma unroll 8
    for (int dc = 0; dc < 32; dc++) {
        float4 xv = X4[dc];
        float xs[4] = {xv.x, xv.y, xv.z, xv.w};
        #pragma unroll
        for (int j = 0; j < 4; j++) {
            int d = dc * 4 + j;
            float xj = xs[j];
            y0 = f4fma(xj, Ws[d * 4 + 0], y0);
            y1 = f4fma(xj, Ws[d * 4 + 1], y1);
            y2 = f4fma(xj, Ws[d * 4 + 2], y2);
            y3 = f4fma(xj, Ws[d * 4 + 3], y3);
        }
    }
    float4* Yp = (float4*)(Y + (size_t)n * HH);
    Yp[0] = y0; Yp[1] = y1; Yp[2] = y2; Yp[3] = y3;
}

// ---- out[n][0:16] = sum_e vals[e]*hin[col[e]][0:16]; 4 lanes/node.
//      Depth-2 software pipeline: group B's index load + 4 gathers issue
//      before group A's gather results are consumed (8 gathers in flight). ----
template <bool RELU, bool BIAS>
__launch_bounds__(256)
__global__ void spmm16(const int* __restrict__ rp, const int* __restrict__ col,
                       const float* __restrict__ vals, const float* __restrict__ hin,
                       const float* __restrict__ bias, float* __restrict__ out) {
    int node = blockIdx.x * 64 + (threadIdx.x >> 2);
    int f = threadIdx.x & 3;
    if (node >= NN) return;
    int s = rp[node], e = rp[node + 1];
    const float4* h4 = (const float4*)hin;
    float4 acc = {0, 0, 0, 0};
    int j = s;
    int sa = min((s + 3) & ~3, e);   // align to 16B for vector edge loads
    for (; j < sa; j++)
        acc = f4fma(vals[j], h4[(size_t)col[j] * 4 + f], acc);
    int4 cA; float4 vA, gA0, gA1, gA2, gA3;
    bool haveA = (j + 3 < e);
    if (haveA) {
        cA = *(const int4*)(col + j);
        vA = *(const float4*)(vals + j);
        gA0 = h4[(size_t)cA.x * 4 + f];
        gA1 = h4[(size_t)cA.y * 4 + f];
        gA2 = h4[(size_t)cA.z * 4 + f];
        gA3 = h4[(size_t)cA.w * 4 + f];
        j += 4;
        while (j + 3 < e) {
            int4   cB = *(const int4*)(col + j);
            float4 vB = *(const float4*)(vals + j);
            float4 gB0 = h4[(size_t)cB.x * 4 + f];
            float4 gB1 = h4[(size_t)cB.y * 4 + f];
            float4 gB2 = h4[(size_t)cB.z * 4 + f];
            float4 gB3 = h4[(size_t)cB.w * 4 + f];
            acc = f4fma(vA.x, gA0, acc);
            acc = f4fma(vA.y, gA1, acc);
            acc = f4fma(vA.z, gA2, acc);
            acc = f4fma(vA.w, gA3, acc);
            vA = vB;
            gA0 = gB0; gA1 = gB1; gA2 = gB2; gA3 = gB3;
            j += 4;
        }
        acc = f4fma(vA.x, gA0, acc);
        acc = f4fma(vA.y, gA1, acc);
        acc = f4fma(vA.z, gA2, acc);
        acc = f4fma(vA.w, gA3, acc);
    }
    for (; j < e; j++)
        acc = f4fma(vals[j], h4[(size_t)col[j] * 4 + f], acc);
    if (BIAS) {
        float4 b = ((const float4*)bias)[f];
        acc.x += b.x; acc.y += b.y; acc.z += b.z; acc.w += b.w;
    }
    if (RELU) {
        acc.x = fmaxf(acc.x, 0.f); acc.y = fmaxf(acc.y, 0.f);
        acc.z = fmaxf(acc.z, 0.f); acc.w = fmaxf(acc.w, 0.f);
    }
    ((float4*)out)[(size_t)node * 4 + f] = acc;
}

// GS[0..255] = G = U^T U, GS[256..271] = colsum(U)
__launch_bounds__(256)
__global__ void stats_gram(const float* __restrict__ U, float* __restrict__ GS) {
    __shared__ float Us[64 * 20];
    int t = threadIdx.x;
    int k = t & 15, kp = t >> 4;
    float g = 0.f, s = 0.f;
    const int npb = (NN + gridDim.x - 1) / gridDim.x;
    int n0 = blockIdx.x * npb;
    int n1 = min(n0 + npb, NN);
    for (int nb = n0; nb < n1; nb += 64) {
        int cnt = min(64, n1 - nb);
        __syncthreads();
        for (int i = t; i < cnt * 4; i += 256) {
            int r = i >> 2, qq = i & 3;
            ((float4*)&Us[r * 20])[qq] = ((const float4*)(U + (size_t)(nb + r) * HH))[qq];
        }
        __syncthreads();
        for (int n = 0; n < cnt; n++) {
            float a = Us[n * 20 + k];
            float b = Us[n * 20 + kp];
            g = fmaf(a, b, g);
            s += a;
        }
    }
    atomicAdd(&GS[kp * 16 + k], g);
    if (kp == 0) atomicAdd(&GS[256 + k], s);
}

// ---- Y = relu(BN(U@W2 + b2)) @ W1n ; 8 threads/node x 4 nodes/thread ----
__launch_bounds__(256)
__global__ void fused_mid(const float* __restrict__ U, const float* __restrict__ GS,
                          const float* __restrict__ W2, const float* __restrict__ b2,
                          const float* __restrict__ gamma, const float* __restrict__ beta,
                          const float* __restrict__ W1n, float* __restrict__ Y) {
    __shared__ float4 W2s[HH * 32];      // (k,dw) at k*32 + permW2(dw)
    __shared__ float4 W1s[DD * 4];       // (d,q)  at d*4 + ((q + (d>>4)) & 3)
    __shared__ float4 SC4[32], SH4[32];  // permW2 layout
    __shared__ float  Gs[272];
    int t = threadIdx.x;
    for (int i = t; i < HH * 32; i += 256) {
        int k = i >> 5, dw = i & 31;
        W2s[k * 32 + permW2(dw)] = ((const float4*)W2)[i];
    }
    for (int i = t; i < DD * 4; i += 256) {
        int d = i >> 2, q = i & 3;
        W1s[d * 4 + ((q + (d >> 4)) & 3)] = ((const float4*)W1n)[i];
    }
    for (int i = t; i < 272; i += 256) Gs[i] = GS[i];
    __syncthreads();
    if (t < DD) {
        int d = t;
        float w[16];
        #pragma unroll
        for (int k = 0; k < 16; k++) w[k] = W2[k * DD + d];
        float sdot = 0.f, quad = 0.f;
        #pragma unroll
        for (int k = 0; k < 16; k++) {
            sdot = fmaf(Gs[256 + k], w[k], sdot);
            float vk = 0.f;
            #pragma unroll
            for (int kp = 0; kp < 16; kp++) vk = fmaf(Gs[k * 16 + kp], w[kp], vk);
            quad = fmaf(w[k], vk, quad);
        }
        float b = b2[d];
        float sumH  = sdot + (float)NN * b;
        float sumsq = quad + 2.f * b * sdot + (float)NN * b * b;
        float mean = sumH * (1.f / NN);
        float var  = sumsq * (1.f / NN) - mean * mean;
        float inv  = rsqrtf(var + 1e-5f);
        float gm = gamma[d] * inv;
        int loc = permW2(d >> 2), jj = d & 3;
        ((float*)&SC4[loc])[jj] = gm;
        ((float*)&SH4[loc])[jj] = (b - mean) * gm + beta[d];
    }
    __syncthreads();
    int g = t >> 3, p = t & 7;
    int base = blockIdx.x * 128;
    int n[4]; bool v[4];
    #pragma unroll
    for (int i = 0; i < 4; i++) { n[i] = base + i * 32 + g; v[i] = n[i] < NN; }
    float u[4][16];
    #pragma unroll
    for (int i = 0; i < 4; i++) {
        if (v[i]) {
            const float4* up = (const float4*)(U + (size_t)n[i] * HH);
            float4 a = up[0], b = up[1], c = up[2], d = up[3];
            u[i][0]=a.x; u[i][1]=a.y; u[i][2]=a.z; u[i][3]=a.w;
            u[i][4]=b.x; u[i][5]=b.y; u[i][6]=b.z; u[i][7]=b.w;
            u[i][8]=c.x; u[i][9]=c.y; u[i][10]=c.z; u[i][11]=c.w;
            u[i][12]=d.x; u[i][13]=d.y; u[i][14]=d.z; u[i][15]=d.w;
        } else {
            #pragma unroll
            for (int k = 0; k < 16; k++) u[i][k] = 0.f;
        }
    }
    float4 y[4][4];
    #pragma unroll
    for (int i = 0; i < 4; i++)
        #pragma unroll
        for (int q = 0; q < 4; q++) y[i][q] = {0, 0, 0, 0};
    #pragma unroll
    for (int dqi = 0; dqi < 4; dqi++) {
        int rpos = p + (dqi << 3);        // permW2(p*4+dqi)
        float4 h[4];
        #pragma unroll
        for (int i = 0; i < 4; i++) h[i] = {0, 0, 0, 0};
        #pragma unroll
        for (int k = 0; k < 16; k++) {
            float4 w = W2s[k * 32 + rpos];
            h[0] = f4fma(u[0][k], w, h[0]);
            h[1] = f4fma(u[1][k], w, h[1]);
            h[2] = f4fma(u[2][k], w, h[2]);
            h[3] = f4fma(u[3][k], w, h[3]);
        }
        float4 s4 = SC4[rpos], t4 = SH4[rpos];
        #pragma unroll
        for (int i = 0; i < 4; i++) {
            h[i].x = fmaxf(fmaf(h[i].x, s4.x, t4.x), 0.f);
            h[i].y = fmaxf(fmaf(h[i].y, s4.y, t4.y), 0.f);
            h[i].z = fmaxf(fmaf(h[i].z, s4.z, t4.z), 0.f);
            h[i].w = fmaxf(fmaf(h[i].w, s4.w, t4.w), 0.f);
        }
        int dq = (p << 2) + dqi;
        #pragma unroll
        for (int j = 0; j < 4; j++) {
            int d = (dq << 2) + j;
            float4 w0 = W1s[d * 4 + ((0 + p) & 3)];
            float4 w1 = W1s[d * 4 + ((1 + p) & 3)];
            float4 w2 = W1s[d * 4 + ((2 + p) & 3)];
            float4 w3 = W1s[d * 4 + ((3 + p) & 3)];
            float h0 = j == 0 ? h[0].x : j == 1 ? h[0].y : j == 2 ? h[0].z : h[0].w;
            float h1 = j == 0 ? h[1].x : j == 1 ? h[1].y : j == 2 ? h[1].z : h[1].w;
            float h2 = j == 0 ? h[2].x : j == 1 ? h[2].y : j == 2 ? h[2].z : h[2].w;
            float h3 = j == 0 ? h[3].x : j == 1 ? h[3].y : j == 2 ? h[3].z : h[3].w;
            y[0][0] = f4fma(h0, w0, y[0][0]); y[0][1] = f4fma(h0, w1, y[0][1]);
            y[0][2] = f4fma(h0, w2, y[0][2]); y[0][3] = f4fma(h0, w3, y[0][3]);
            y[1][0] = f4fma(h1, w0, y[1][0]); y[1][1] = f4fma(h1, w1, y[1][1]);
            y[1][2] = f4fma(h1, w2, y[1][2]); y[1][3] = f4fma(h1, w3, y[1][3]);
            y[2][0] = f4fma(h2, w0, y[2][0]); y[2][1] = f4fma(h2, w1, y[2][1]);
            y[2][2] = f4fma(h2, w2, y[2][2]); y[2][3] = f4fma(h2, w3, y[2][3]);
            y[3][0] = f4fma(h3, w0, y[3][0]); y[3][1] = f4fma(h3, w1, y[3][1]);
            y[3][2] = f4fma(h3, w2, y[3][2]); y[3][3] = f4fma(h3, w3, y[3][3]);
        }
    }
    #pragma unroll
    for (int i = 0; i < 4; i++)
        #pragma unroll
        for (int q = 0; q < 4; q++) {
            float4& a = y[i][q];
            a.x += __shfl_xor(a.x, 1); a.y += __shfl_xor(a.y, 1);
            a.z += __shfl_xor(a.z, 1); a.w += __shfl_xor(a.w, 1);
            a.x += __shfl_xor(a.x, 2); a.y += __shfl_xor(a.y, 2);
            a.z += __shfl_xor(a.z, 2); a.w += __shfl_xor(a.w, 2);
            a.x += __shfl_xor(a.x, 4); a.y += __shfl_xor(a.y, 4);
            a.z += __shfl_xor(a.z, 4); a.w += __shfl_xor(a.w, 4);
        }
    int wi = p >> 1, q0 = (p & 1) * 2;
    if (v[wi]) {
        ((float4*)Y)[(size_t)n[wi] * 4 + q0]     = y[wi][q0];
        ((float4*)Y)[(size_t)n[wi] * 4 + q0 + 1] = y[wi][q0 + 1];
    }
}

// ---- out = U @ W + bias (N x 16)@(16 x 40); 4 threads/node, 10 cols each ----
__launch_bounds__(256)
__global__ void gemm_hc_reg(const float* __restrict__ U, const float* __restrict__ W,
                            const float* __restrict__ bias, float* __restrict__ out) {
    __shared__ float2 Ws[HH * 20];
    __shared__ float2 Bs[20];
    int t = threadIdx.x;
    for (int i = t; i < HH * 20; i += 256) Ws[i] = ((const float2*)W)[i];
    if (t < 20) Bs[t] = ((const float2*)bias)[t];
    __syncthreads();
    int node = blockIdx.x * 64 + (t >> 2);
    int p = t & 3;
    if (node >= NN) return;
    float u[16];
    {
        const float4* up = (const float4*)(U + (size_t)node * HH);
        float4 a = up[0], b = up[1], c = up[2], d = up[3];
        u[0]=a.x; u[1]=a.y; u[2]=a.z; u[3]=a.w; u[4]=b.x; u[5]=b.y; u[6]=b.z; u[7]=b.w;
        u[8]=c.x; u[9]=c.y; u[10]=c.z; u[11]=c.w; u[12]=d.x; u[13]=d.y; u[14]=d.z; u[15]=d.w;
    }
    float2 acc[5];
    #pragma unroll
    for (int i = 0; i < 5; i++) acc[i] = Bs[p * 5 + i];
    #pragma unroll
    for (int k = 0; k < 16; k++) {
        float uk = u[k];
        #pragma unroll
        for (int i = 0; i < 5; i++) {
            float2 w = Ws[k * 20 + p * 5 + i];
            acc[i].x = fmaf(uk, w.x, acc[i].x);
            acc[i].y = fmaf(uk, w.y, acc[i].y);
        }
    }
    float2* O = (float2*)(out + (size_t)node * CC) + p * 5;
    #pragma unroll
    for (int i = 0; i < 5; i++) O[i] = acc[i];
}

extern "C" void kernel_launch(void* const* d_in, const int* in_sizes, int n_in,
                              void* d_out, int out_size, void* d_ws, size_t ws_size,
                              hipStream_t stream) {
    const float* x     = (const float*)d_in[0];
    const float* vals  = (const float*)d_in[1];
    const float* W1    = (const float*)d_in[2];
    const float* b1    = (const float*)d_in[3];
    const float* W2    = (const float*)d_in[4];
    const float* b2    = (const float*)d_in[5];
    const float* gamma = (const float*)d_in[6];
    const float* beta  = (const float*)d_in[7];
    const float* W1f   = (const float*)d_in[8];
    const float* b1f   = (const float*)d_in[9];
    const float* W2f   = (const float*)d_in[10];
    const float* b2f   = (const float*)d_in[11];
    const int*   row   = (const int*)d_in[12];
    const int*   col   = (const int*)d_in[13];
    float* out = (float*)d_out;

    char* ws = (char*)d_ws;
    size_t off = 0;
    auto alloc = [&](size_t bytes) -> char* {
        char* p = ws + off;
        off += (bytes + 255) / 256 * 256;
        return p;
    };
    int*   rp = (int*)  alloc((NN + 1) * sizeof(int));
    float* GS = (float*)alloc(LL * 272 * sizeof(float));
    float* Y  = (float*)alloc((size_t)NN * HH * sizeof(float));
    float* T  = (float*)alloc((size_t)NN * HH * sizeof(float));
    float* U  = (float*)alloc((size_t)NN * HH * sizeof(float));

    build_rowptr<<<(NE + 255) / 256, 256, 0, stream>>>(row, rp);
    zero_buf<<<(LL * 272 + 255) / 256, 256, 0, stream>>>(GS, LL * 272);

    gemm_dh_reg<<<(NN + 255) / 256, 256, 0, stream>>>(x, W1, Y);
    for (int l = 0; l < LL; l++) {
        spmm16<true, true><<<(NN + 63) / 64, 256, 0, stream>>>(rp, col, vals, Y, b1 + l * HH, T);
        spmm16<false, false><<<(NN + 63) / 64, 256, 0, stream>>>(rp, col, vals, T, nullptr, U);
        stats_gram<<<512, 256, 0, stream>>>(U, GS + l * 272);
        const float* W1next = (l < LL - 1) ? (W1 + (l + 1) * DD * HH) : W1f;
        fused_mid<<<(NN + 127) / 128, 256, 0, stream>>>(U, GS + l * 272,
            W2 + l * HH * DD, b2 + l * DD, gamma + l * DD, beta + l * DD, W1next, Y);
    }
    spmm16<true, true><<<(NN + 63) / 64, 256, 0, stream>>>(rp, col, vals, Y, b1f, T);
    spmm16<false, false><<<(NN + 63) / 64, 256, 0, stream>>>(rp, col, vals, T, nullptr, U);
    gemm_hc_reg<<<(NN + 63) / 64, 256, 0, stream>>>(U, W2f, b2f, out);
}

// Round 8
// 514.023 us; speedup vs baseline: 1.1759x; 1.0257x over previous
//
#include <hip/hip_runtime.h>

#define NN 100000
#define NE 1600000
#define DD 128
#define HH 16
#define CC 40
#define LL 3

typedef int   vi4 __attribute__((ext_vector_type(4)));
typedef float vf4 __attribute__((ext_vector_type(4)));

__device__ __forceinline__ float4 f4fma(float s, float4 w, float4 a) {
    a.x = fmaf(s, w.x, a.x); a.y = fmaf(s, w.y, a.y);
    a.z = fmaf(s, w.z, a.z); a.w = fmaf(s, w.w, a.w);
    return a;
}

// bf16 helpers (RNE pack, shift unpack)
__device__ __forceinline__ unsigned short f2bf(float f) {
    unsigned u = __float_as_uint(f);
    unsigned r = u + 0x7fffu + ((u >> 16) & 1u);
    return (unsigned short)(r >> 16);
}
__device__ __forceinline__ unsigned pk2(float a, float b) {
    return (unsigned)f2bf(a) | ((unsigned)f2bf(b) << 16);
}
__device__ __forceinline__ float bflo(unsigned u) { return __uint_as_float(u << 16); }
__device__ __forceinline__ float bfhi(unsigned u) { return __uint_as_float(u & 0xffff0000u); }

// perm for [*][32]-float4 LDS arrays read at dw = p*4+dqi by 8 lanes p=0..7
__device__ __forceinline__ int permW2(int dw) {
    return (dw >> 2) | ((dw & 3) << 3);
}

// Edge-centric rowptr: rp[i] = first edge e with row[e] >= i (row sorted).
__global__ void build_rowptr(const int* __restrict__ row, int* __restrict__ rp) {
    int e = blockIdx.x * 256 + threadIdx.x;
    if (e >= NE) return;
    int r1 = row[e];
    int r0 = (e == 0) ? -1 : row[e - 1];
    for (int i = r0 + 1; i <= r1; i++) rp[i] = e;
    if (e == NE - 1) {
        for (int i = r1 + 1; i <= NN; i++) rp[i] = NE;
    }
}

__global__ void zero_buf(float* __restrict__ s, int n) {
    int i = blockIdx.x * 256 + threadIdx.x;
    if (i < n) s[i] = 0.f;
}

// ---- Y(bf16) = X @ W  (N x 128)@(128 x 16); thread-per-node ----
__launch_bounds__(256)
__global__ void gemm_dh_reg(const float* __restrict__ X, const float* __restrict__ W,
                            unsigned* __restrict__ Y) {
    __shared__ float4 Ws[DD * 4];
    int t = threadIdx.x;
    for (int i = t; i < DD * 4; i += 256) Ws[i] = ((const float4*)W)[i];
    __syncthreads();
    int n = blockIdx.x * 256 + t;
    if (n >= NN) return;
    const float4* X4 = (const float4*)(X + (size_t)n * DD);
    float4 y0 = {0,0,0,0}, y1 = {0,0,0,0}, y2 = {0,0,0,0}, y3 = {0,0,0,0};
    #pragma unroll 8
    for (int dc = 0; dc < 32; dc++) {
        float4 xv = X4[dc];
        float xs[4] = {xv.x, xv.y, xv.z, xv.w};
        #pragma unroll
        for (int j = 0; j < 4; j++) {
            int d = dc * 4 + j;
            float xj = xs[j];
            y0 = f4fma(xj, Ws[d * 4 + 0], y0);
            y1 = f4fma(xj, Ws[d * 4 + 1], y1);
            y2 = f4fma(xj, Ws[d * 4 + 2], y2);
            y3 = f4fma(xj, Ws[d * 4 + 3], y3);
        }
    }
    uint4 o0 = {pk2(y0.x, y0.y), pk2(y0.z, y0.w), pk2(y1.x, y1.y), pk2(y1.z, y1.w)};
    uint4 o1 = {pk2(y2.x, y2.y), pk2(y2.z, y2.w), pk2(y3.x, y3.y), pk2(y3.z, y3.w)};
    ((uint4*)Y)[(size_t)n * 2]     = o0;
    ((uint4*)Y)[(size_t)n * 2 + 1] = o1;
}

// ---- spmm over bf16 table: out[n][0:16] = sum vals[e]*hin[col[e]][0:16]
//      4 lanes/node; nt streaming edge loads; depth-2 gather pipeline. ----
template <bool RELU, bool BIAS, bool OBF>
__launch_bounds__(256)
__global__ void spmm16(const int* __restrict__ rp, const int* __restrict__ col,
                       const float* __restrict__ vals, const unsigned* __restrict__ hin,
                       const float* __restrict__ bias, void* __restrict__ outv) {
    int node = blockIdx.x * 64 + (threadIdx.x >> 2);
    int f = threadIdx.x & 3;
    if (node >= NN) return;
    int s = rp[node], e = rp[node + 1];
    const uint2* h2 = (const uint2*)hin;     // row = 4 x uint2 (16 bf16)
    float4 acc = {0, 0, 0, 0};
    int j = s;
    int sa = min((s + 3) & ~3, e);
    for (; j < sa; j++) {
        uint2 g = h2[(size_t)col[j] * 4 + f];
        float v = vals[j];
        acc.x = fmaf(v, bflo(g.x), acc.x); acc.y = fmaf(v, bfhi(g.x), acc.y);
        acc.z = fmaf(v, bflo(g.y), acc.z); acc.w = fmaf(v, bfhi(g.y), acc.w);
    }
    if (j + 3 < e) {
        vi4 cA = __builtin_nontemporal_load((const vi4*)(col + j));
        vf4 vA = __builtin_nontemporal_load((const vf4*)(vals + j));
        uint2 gA0 = h2[(size_t)cA.x * 4 + f];
        uint2 gA1 = h2[(size_t)cA.y * 4 + f];
        uint2 gA2 = h2[(size_t)cA.z * 4 + f];
        uint2 gA3 = h2[(size_t)cA.w * 4 + f];
        j += 4;
        while (j + 3 < e) {
            vi4 cB = __builtin_nontemporal_load((const vi4*)(col + j));
            vf4 vB = __builtin_nontemporal_load((const vf4*)(vals + j));
            uint2 gB0 = h2[(size_t)cB.x * 4 + f];
            uint2 gB1 = h2[(size_t)cB.y * 4 + f];
            uint2 gB2 = h2[(size_t)cB.z * 4 + f];
            uint2 gB3 = h2[(size_t)cB.w * 4 + f];
            acc.x = fmaf(vA.x, bflo(gA0.x), acc.x); acc.y = fmaf(vA.x, bfhi(gA0.x), acc.y);
            acc.z = fmaf(vA.x, bflo(gA0.y), acc.z); acc.w = fmaf(vA.x, bfhi(gA0.y), acc.w);
            acc.x = fmaf(vA.y, bflo(gA1.x), acc.x); acc.y = fmaf(vA.y, bfhi(gA1.x), acc.y);
            acc.z = fmaf(vA.y, bflo(gA1.y), acc.z); acc.w = fmaf(vA.y, bfhi(gA1.y), acc.w);
            acc.x = fmaf(vA.z, bflo(gA2.x), acc.x); acc.y = fmaf(vA.z, bfhi(gA2.x), acc.y);
            acc.z = fmaf(vA.z, bflo(gA2.y), acc.z); acc.w = fmaf(vA.z, bfhi(gA2.y), acc.w);
            acc.x = fmaf(vA.w, bflo(gA3.x), acc.x); acc.y = fmaf(vA.w, bfhi(gA3.x), acc.y);
            acc.z = fmaf(vA.w, bflo(gA3.y), acc.z); acc.w = fmaf(vA.w, bfhi(gA3.y), acc.w);
            vA = vB;
            gA0 = gB0; gA1 = gB1; gA2 = gB2; gA3 = gB3;
            j += 4;
        }
        acc.x = fmaf(vA.x, bflo(gA0.x), acc.x); acc.y = fmaf(vA.x, bfhi(gA0.x), acc.y);
        acc.z = fmaf(vA.x, bflo(gA0.y), acc.z); acc.w = fmaf(vA.x, bfhi(gA0.y), acc.w);
        acc.x = fmaf(vA.y, bflo(gA1.x), acc.x); acc.y = fmaf(vA.y, bfhi(gA1.x), acc.y);
        acc.z = fmaf(vA.y, bflo(gA1.y), acc.z); acc.w = fmaf(vA.y, bfhi(gA1.y), acc.w);
        acc.x = fmaf(vA.z, bflo(gA2.x), acc.x); acc.y = fmaf(vA.z, bfhi(gA2.x), acc.y);
        acc.z = fmaf(vA.z, bflo(gA2.y), acc.z); acc.w = fmaf(vA.z, bfhi(gA2.y), acc.w);
        acc.x = fmaf(vA.w, bflo(gA3.x), acc.x); acc.y = fmaf(vA.w, bfhi(gA3.x), acc.y);
        acc.z = fmaf(vA.w, bflo(gA3.y), acc.z); acc.w = fmaf(vA.w, bfhi(gA3.y), acc.w);
    }
    for (; j < e; j++) {
        uint2 g = h2[(size_t)col[j] * 4 + f];
        float v = vals[j];
        acc.x = fmaf(v, bflo(g.x), acc.x); acc.y = fmaf(v, bfhi(g.x), acc.y);
        acc.z = fmaf(v, bflo(g.y), acc.z); acc.w = fmaf(v, bfhi(g.y), acc.w);
    }
    if (BIAS) {
        float4 b = ((const float4*)bias)[f];
        acc.x += b.x; acc.y += b.y; acc.z += b.z; acc.w += b.w;
    }
    if (RELU) {
        acc.x = fmaxf(acc.x, 0.f); acc.y = fmaxf(acc.y, 0.f);
        acc.z = fmaxf(acc.z, 0.f); acc.w = fmaxf(acc.w, 0.f);
    }
    if (OBF) {
        uint2 o = {pk2(acc.x, acc.y), pk2(acc.z, acc.w)};
        ((uint2*)outv)[(size_t)node * 4 + f] = o;
    } else {
        ((float4*)outv)[(size_t)node * 4 + f] = acc;
    }
}

// GS[0..255] = G = U^T U, GS[256..271] = colsum(U)   (U is f32)
__launch_bounds__(256)
__global__ void stats_gram(const float* __restrict__ U, float* __restrict__ GS) {
    __shared__ float Us[64 * 20];
    int t = threadIdx.x;
    int k = t & 15, kp = t >> 4;
    float g = 0.f, s = 0.f;
    const int npb = (NN + gridDim.x - 1) / gridDim.x;
    int n0 = blockIdx.x * npb;
    int n1 = min(n0 + npb, NN);
    for (int nb = n0; nb < n1; nb += 64) {
        int cnt = min(64, n1 - nb);
        __syncthreads();
        for (int i = t; i < cnt * 4; i += 256) {
            int r = i >> 2, qq = i & 3;
            ((float4*)&Us[r * 20])[qq] = ((const float4*)(U + (size_t)(nb + r) * HH))[qq];
        }
        __syncthreads();
        for (int n = 0; n < cnt; n++) {
            float a = Us[n * 20 + k];
            float b = Us[n * 20 + kp];
            g = fmaf(a, b, g);
            s += a;
        }
    }
    atomicAdd(&GS[kp * 16 + k], g);
    if (kp == 0) atomicAdd(&GS[256 + k], s);
}

// ---- Y(bf16) = relu(BN(U@W2 + b2)) @ W1n ; 8 threads/node x 4 nodes/thread ----
__launch_bounds__(256)
__global__ void fused_mid(const float* __restrict__ U, const float* __restrict__ GS,
                          const float* __restrict__ W2, const float* __restrict__ b2,
                          const float* __restrict__ gamma, const float* __restrict__ beta,
                          const float* __restrict__ W1n, unsigned* __restrict__ Y) {
    __shared__ float4 W2s[HH * 32];
    __shared__ float4 W1s[DD * 4];
    __shared__ float4 SC4[32], SH4[32];
    __shared__ float  Gs[272];
    int t = threadIdx.x;
    for (int i = t; i < HH * 32; i += 256) {
        int k = i >> 5, dw = i & 31;
        W2s[k * 32 + permW2(dw)] = ((const float4*)W2)[i];
    }
    for (int i = t; i < DD * 4; i += 256) {
        int d = i >> 2, q = i & 3;
        W1s[d * 4 + ((q + (d >> 4)) & 3)] = ((const float4*)W1n)[i];
    }
    for (int i = t; i < 272; i += 256) Gs[i] = GS[i];
    __syncthreads();
    if (t < DD) {
        int d = t;
        float w[16];
        #pragma unroll
        for (int k = 0; k < 16; k++) w[k] = W2[k * DD + d];
        float sdot = 0.f, quad = 0.f;
        #pragma unroll
        for (int k = 0; k < 16; k++) {
            sdot = fmaf(Gs[256 + k], w[k], sdot);
            float vk = 0.f;
            #pragma unroll
            for (int kp = 0; kp < 16; kp++) vk = fmaf(Gs[k * 16 + kp], w[kp], vk);
            quad = fmaf(w[k], vk, quad);
        }
        float b = b2[d];
        float sumH  = sdot + (float)NN * b;
        float sumsq = quad + 2.f * b * sdot + (float)NN * b * b;
        float mean = sumH * (1.f / NN);
        float var  = sumsq * (1.f / NN) - mean * mean;
        float inv  = rsqrtf(var + 1e-5f);
        float gm = gamma[d] * inv;
        int loc = permW2(d >> 2), jj = d & 3;
        ((float*)&SC4[loc])[jj] = gm;
        ((float*)&SH4[loc])[jj] = (b - mean) * gm + beta[d];
    }
    __syncthreads();
    int g = t >> 3, p = t & 7;
    int base = blockIdx.x * 128;
    int n[4]; bool v[4];
    #pragma unroll
    for (int i = 0; i < 4; i++) { n[i] = base + i * 32 + g; v[i] = n[i] < NN; }
    float u[4][16];
    #pragma unroll
    for (int i = 0; i < 4; i++) {
        if (v[i]) {
            const float4* up = (const float4*)(U + (size_t)n[i] * HH);
            float4 a = up[0], b = up[1], c = up[2], d = up[3];
            u[i][0]=a.x; u[i][1]=a.y; u[i][2]=a.z; u[i][3]=a.w;
            u[i][4]=b.x; u[i][5]=b.y; u[i][6]=b.z; u[i][7]=b.w;
            u[i][8]=c.x; u[i][9]=c.y; u[i][10]=c.z; u[i][11]=c.w;
            u[i][12]=d.x; u[i][13]=d.y; u[i][14]=d.z; u[i][15]=d.w;
        } else {
            #pragma unroll
            for (int k = 0; k < 16; k++) u[i][k] = 0.f;
        }
    }
    float4 y[4][4];
    #pragma unroll
    for (int i = 0; i < 4; i++)
        #pragma unroll
        for (int q = 0; q < 4; q++) y[i][q] = {0, 0, 0, 0};
    #pragma unroll
    for (int dqi = 0; dqi < 4; dqi++) {
        int rpos = p + (dqi << 3);
        float4 h[4];
        #pragma unroll
        for (int i = 0; i < 4; i++) h[i] = {0, 0, 0, 0};
        #pragma unroll
        for (int k = 0; k < 16; k++) {
            float4 w = W2s[k * 32 + rpos];
            h[0] = f4fma(u[0][k], w, h[0]);
            h[1] = f4fma(u[1][k], w, h[1]);
            h[2] = f4fma(u[2][k], w, h[2]);
            h[3] = f4fma(u[3][k], w, h[3]);
        }
        float4 s4 = SC4[rpos], t4 = SH4[rpos];
        #pragma unroll
        for (int i = 0; i < 4; i++) {
            h[i].x = fmaxf(fmaf(h[i].x, s4.x, t4.x), 0.f);
            h[i].y = fmaxf(fmaf(h[i].y, s4.y, t4.y), 0.f);
            h[i].z = fmaxf(fmaf(h[i].z, s4.z, t4.z), 0.f);
            h[i].w = fmaxf(fmaf(h[i].w, s4.w, t4.w), 0.f);
        }
        int dq = (p << 2) + dqi;
        #pragma unroll
        for (int j = 0; j < 4; j++) {
            int d = (dq << 2) + j;
            float4 w0 = W1s[d * 4 + ((0 + p) & 3)];
            float4 w1 = W1s[d * 4 + ((1 + p) & 3)];
            float4 w2 = W1s[d * 4 + ((2 + p) & 3)];
            float4 w3 = W1s[d * 4 + ((3 + p) & 3)];
            float h0 = j == 0 ? h[0].x : j == 1 ? h[0].y : j == 2 ? h[0].z : h[0].w;
            float h1 = j == 0 ? h[1].x : j == 1 ? h[1].y : j == 2 ? h[1].z : h[1].w;
            float h2 = j == 0 ? h[2].x : j == 1 ? h[2].y : j == 2 ? h[2].z : h[2].w;
            float h3 = j == 0 ? h[3].x : j == 1 ? h[3].y : j == 2 ? h[3].z : h[3].w;
            y[0][0] = f4fma(h0, w0, y[0][0]); y[0][1] = f4fma(h0, w1, y[0][1]);
            y[0][2] = f4fma(h0, w2, y[0][2]); y[0][3] = f4fma(h0, w3, y[0][3]);
            y[1][0] = f4fma(h1, w0, y[1][0]); y[1][1] = f4fma(h1, w1, y[1][1]);
            y[1][2] = f4fma(h1, w2, y[1][2]); y[1][3] = f4fma(h1, w3, y[1][3]);
            y[2][0] = f4fma(h2, w0, y[2][0]); y[2][1] = f4fma(h2, w1, y[2][1]);
            y[2][2] = f4fma(h2, w2, y[2][2]); y[2][3] = f4fma(h2, w3, y[2][3]);
            y[3][0] = f4fma(h3, w0, y[3][0]); y[3][1] = f4fma(h3, w1, y[3][1]);
            y[3][2] = f4fma(h3, w2, y[3][2]); y[3][3] = f4fma(h3, w3, y[3][3]);
        }
    }
    #pragma unroll
    for (int i = 0; i < 4; i++)
        #pragma unroll
        for (int q = 0; q < 4; q++) {
            float4& a = y[i][q];
            a.x += __shfl_xor(a.x, 1); a.y += __shfl_xor(a.y, 1);
            a.z += __shfl_xor(a.z, 1); a.w += __shfl_xor(a.w, 1);
            a.x += __shfl_xor(a.x, 2); a.y += __shfl_xor(a.y, 2);
            a.z += __shfl_xor(a.z, 2); a.w += __shfl_xor(a.w, 2);
            a.x += __shfl_xor(a.x, 4); a.y += __shfl_xor(a.y, 4);
            a.z += __shfl_xor(a.z, 4); a.w += __shfl_xor(a.w, 4);
        }
    int wi = p >> 1, q0 = (p & 1) * 2;
    if (v[wi]) {
        float4 a = y[wi][q0], b = y[wi][q0 + 1];
        uint4 o = {pk2(a.x, a.y), pk2(a.z, a.w), pk2(b.x, b.y), pk2(b.z, b.w)};
        ((uint4*)Y)[(size_t)n[wi] * 2 + (q0 >> 1)] = o;
    }
}

// ---- out = U @ W + bias (N x 16)@(16 x 40); 4 threads/node, 10 cols each ----
__launch_bounds__(256)
__global__ void gemm_hc_reg(const float* __restrict__ U, const float* __restrict__ W,
                            const float* __restrict__ bias, float* __restrict__ out) {
    __shared__ float2 Ws[HH * 20];
    __shared__ float2 Bs[20];
    int t = threadIdx.x;
    for (int i = t; i < HH * 20; i += 256) Ws[i] = ((const float2*)W)[i];
    if (t < 20) Bs[t] = ((const float2*)bias)[t];
    __syncthreads();
    int node = blockIdx.x * 64 + (t >> 2);
    int p = t & 3;
    if (node >= NN) return;
    float u[16];
    {
        const float4* up = (const float4*)(U + (size_t)node * HH);
        float4 a = up[0], b = up[1], c = up[2], d = up[3];
        u[0]=a.x; u[1]=a.y; u[2]=a.z; u[3]=a.w; u[4]=b.x; u[5]=b.y; u[6]=b.z; u[7]=b.w;
        u[8]=c.x; u[9]=c.y; u[10]=c.z; u[11]=c.w; u[12]=d.x; u[13]=d.y; u[14]=d.z; u[15]=d.w;
    }
    float2 acc[5];
    #pragma unroll
    for (int i = 0; i < 5; i++) acc[i] = Bs[p * 5 + i];
    #pragma unroll
    for (int k = 0; k < 16; k++) {
        float uk = u[k];
        #pragma unroll
        for (int i = 0; i < 5; i++) {
            float2 w = Ws[k * 20 + p * 5 + i];
            acc[i].x = fmaf(uk, w.x, acc[i].x);
            acc[i].y = fmaf(uk, w.y, acc[i].y);
        }
    }
    float2* O = (float2*)(out + (size_t)node * CC) + p * 5;
    #pragma unroll
    for (int i = 0; i < 5; i++) O[i] = acc[i];
}

extern "C" void kernel_launch(void* const* d_in, const int* in_sizes, int n_in,
                              void* d_out, int out_size, void* d_ws, size_t ws_size,
                              hipStream_t stream) {
    const float* x     = (const float*)d_in[0];
    const float* vals  = (const float*)d_in[1];
    const float* W1    = (const float*)d_in[2];
    const float* b1    = (const float*)d_in[3];
    const float* W2    = (const float*)d_in[4];
    const float* b2    = (const float*)d_in[5];
    const float* gamma = (const float*)d_in[6];
    const float* beta  = (const float*)d_in[7];
    const float* W1f   = (const float*)d_in[8];
    const float* b1f   = (const float*)d_in[9];
    const float* W2f   = (const float*)d_in[10];
    const float* b2f   = (const float*)d_in[11];
    const int*   row   = (const int*)d_in[12];
    const int*   col   = (const int*)d_in[13];
    float* out = (float*)d_out;

    char* ws = (char*)d_ws;
    size_t off = 0;
    auto alloc = [&](size_t bytes) -> char* {
        char* p = ws + off;
        off += (bytes + 255) / 256 * 256;
        return p;
    };
    int*      rp = (int*)     alloc((NN + 1) * sizeof(int));
    float*    GS = (float*)   alloc(LL * 272 * sizeof(float));
    unsigned* Yb = (unsigned*)alloc((size_t)NN * HH * 2);   // bf16
    unsigned* Tb = (unsigned*)alloc((size_t)NN * HH * 2);   // bf16
    float*    U  = (float*)   alloc((size_t)NN * HH * sizeof(float));

    build_rowptr<<<(NE + 255) / 256, 256, 0, stream>>>(row, rp);
    zero_buf<<<(LL * 272 + 255) / 256, 256, 0, stream>>>(GS, LL * 272);

    gemm_dh_reg<<<(NN + 255) / 256, 256, 0, stream>>>(x, W1, Yb);
    for (int l = 0; l < LL; l++) {
        spmm16<true, true, true><<<(NN + 63) / 64, 256, 0, stream>>>(rp, col, vals, Yb, b1 + l * HH, Tb);
        spmm16<false, false, false><<<(NN + 63) / 64, 256, 0, stream>>>(rp, col, vals, Tb, nullptr, U);
        stats_gram<<<512, 256, 0, stream>>>(U, GS + l * 272);
        const float* W1next = (l < LL - 1) ? (W1 + (l + 1) * DD * HH) : W1f;
        fused_mid<<<(NN + 127) / 128, 256, 0, stream>>>(U, GS + l * 272,
            W2 + l * HH * DD, b2 + l * DD, gamma + l * DD, beta + l * DD, W1next, Yb);
    }
    spmm16<true, true, true><<<(NN + 63) / 64, 256, 0, stream>>>(rp, col, vals, Yb, b1f, Tb);
    spmm16<false, false, false><<<(NN + 63) / 64, 256, 0, stream>>>(rp, col, vals, Tb, nullptr, U);
    gemm_hc_reg<<<(NN + 63) / 64, 256, 0, stream>>>(U, W2f, b2f, out);
}

// Round 9
// 459.420 us; speedup vs baseline: 1.3157x; 1.1189x over previous
//
#include <hip/hip_runtime.h>

#define NN 100000
#define NE 1600000
#define DD 128
#define HH 16
#define CC 40
#define LL 3

typedef int   vi4 __attribute__((ext_vector_type(4)));
typedef float vf4 __attribute__((ext_vector_type(4)));

__device__ __forceinline__ float4 f4fma(float s, float4 w, float4 a) {
    a.x = fmaf(s, w.x, a.x); a.y = fmaf(s, w.y, a.y);
    a.z = fmaf(s, w.z, a.z); a.w = fmaf(s, w.w, a.w);
    return a;
}

// bf16 helpers (RNE pack, shift unpack)
__device__ __forceinline__ unsigned short f2bf(float f) {
    unsigned u = __float_as_uint(f);
    unsigned r = u + 0x7fffu + ((u >> 16) & 1u);
    return (unsigned short)(r >> 16);
}
__device__ __forceinline__ unsigned pk2(float a, float b) {
    return (unsigned)f2bf(a) | ((unsigned)f2bf(b) << 16);
}
__device__ __forceinline__ float bflo(unsigned u) { return __uint_as_float(u << 16); }
__device__ __forceinline__ float bfhi(unsigned u) { return __uint_as_float(u & 0xffff0000u); }

// perm for [*][32]-float4 LDS arrays read at dw = p*4+dqi by 8 lanes p=0..7
__device__ __forceinline__ int permW2(int dw) {
    return (dw >> 2) | ((dw & 3) << 3);
}

// Edge-centric rowptr: rp[i] = first edge e with row[e] >= i (row sorted).
__global__ void build_rowptr(const int* __restrict__ row, int* __restrict__ rp) {
    int e = blockIdx.x * 256 + threadIdx.x;
    if (e >= NE) return;
    int r1 = row[e];
    int r0 = (e == 0) ? -1 : row[e - 1];
    for (int i = r0 + 1; i <= r1; i++) rp[i] = e;
    if (e == NE - 1) {
        for (int i = r1 + 1; i <= NN; i++) rp[i] = NE;
    }
}

__global__ void zero_buf(float* __restrict__ s, int n) {
    int i = blockIdx.x * 256 + threadIdx.x;
    if (i < n) s[i] = 0.f;
}

// ---- Y(bf16) = X @ W  (N x 128)@(128 x 16); thread-per-node ----
__launch_bounds__(256)
__global__ void gemm_dh_reg(const float* __restrict__ X, const float* __restrict__ W,
                            unsigned* __restrict__ Y) {
    __shared__ float4 Ws[DD * 4];
    int t = threadIdx.x;
    for (int i = t; i < DD * 4; i += 256) Ws[i] = ((const float4*)W)[i];
    __syncthreads();
    int n = blockIdx.x * 256 + t;
    if (n >= NN) return;
    const float4* X4 = (const float4*)(X + (size_t)n * DD);
    float4 y0 = {0,0,0,0}, y1 = {0,0,0,0}, y2 = {0,0,0,0}, y3 = {0,0,0,0};
    #pragma unroll 8
    for (int dc = 0; dc < 32; dc++) {
        float4 xv = X4[dc];
        float xs[4] = {xv.x, xv.y, xv.z, xv.w};
        #pragma unroll
        for (int j = 0; j < 4; j++) {
            int d = dc * 4 + j;
            float xj = xs[j];
            y0 = f4fma(xj, Ws[d * 4 + 0], y0);
            y1 = f4fma(xj, Ws[d * 4 + 1], y1);
            y2 = f4fma(xj, Ws[d * 4 + 2], y2);
            y3 = f4fma(xj, Ws[d * 4 + 3], y3);
        }
    }
    uint4 o0 = {pk2(y0.x, y0.y), pk2(y0.z, y0.w), pk2(y1.x, y1.y), pk2(y1.z, y1.w)};
    uint4 o1 = {pk2(y2.x, y2.y), pk2(y2.z, y2.w), pk2(y3.x, y3.y), pk2(y3.z, y3.w)};
    ((uint4*)Y)[(size_t)n * 2]     = o0;
    ((uint4*)Y)[(size_t)n * 2 + 1] = o1;
}

// ---- spmm over bf16 table; 4 lanes/node; optional fused Gram epilogue ----
template <bool RELU, bool BIAS, bool OBF, bool GRAM>
__launch_bounds__(256)
__global__ void spmm16(const int* __restrict__ rp, const int* __restrict__ col,
                       const float* __restrict__ vals, const unsigned* __restrict__ hin,
                       const float* __restrict__ bias, void* __restrict__ outv,
                       float* __restrict__ GS) {
    int node = blockIdx.x * 64 + (threadIdx.x >> 2);
    int f = threadIdx.x & 3;
    bool valid = node < NN;
    if (!GRAM && !valid) return;
    float4 acc = {0, 0, 0, 0};
    if (valid) {
        int s = rp[node], e = rp[node + 1];
        const uint2* h2 = (const uint2*)hin;
        int j = s;
        int sa = min((s + 3) & ~3, e);
        for (; j < sa; j++) {
            uint2 g = h2[(size_t)col[j] * 4 + f];
            float v = vals[j];
            acc.x = fmaf(v, bflo(g.x), acc.x); acc.y = fmaf(v, bfhi(g.x), acc.y);
            acc.z = fmaf(v, bflo(g.y), acc.z); acc.w = fmaf(v, bfhi(g.y), acc.w);
        }
        if (j + 3 < e) {
            vi4 cA = __builtin_nontemporal_load((const vi4*)(col + j));
            vf4 vA = __builtin_nontemporal_load((const vf4*)(vals + j));
            uint2 gA0 = h2[(size_t)cA.x * 4 + f];
            uint2 gA1 = h2[(size_t)cA.y * 4 + f];
            uint2 gA2 = h2[(size_t)cA.z * 4 + f];
            uint2 gA3 = h2[(size_t)cA.w * 4 + f];
            j += 4;
            while (j + 3 < e) {
                vi4 cB = __builtin_nontemporal_load((const vi4*)(col + j));
                vf4 vB = __builtin_nontemporal_load((const vf4*)(vals + j));
                uint2 gB0 = h2[(size_t)cB.x * 4 + f];
                uint2 gB1 = h2[(size_t)cB.y * 4 + f];
                uint2 gB2 = h2[(size_t)cB.z * 4 + f];
                uint2 gB3 = h2[(size_t)cB.w * 4 + f];
                acc.x = fmaf(vA.x, bflo(gA0.x), acc.x); acc.y = fmaf(vA.x, bfhi(gA0.x), acc.y);
                acc.z = fmaf(vA.x, bflo(gA0.y), acc.z); acc.w = fmaf(vA.x, bfhi(gA0.y), acc.w);
                acc.x = fmaf(vA.y, bflo(gA1.x), acc.x); acc.y = fmaf(vA.y, bfhi(gA1.x), acc.y);
                acc.z = fmaf(vA.y, bflo(gA1.y), acc.z); acc.w = fmaf(vA.y, bfhi(gA1.y), acc.w);
                acc.x = fmaf(vA.z, bflo(gA2.x), acc.x); acc.y = fmaf(vA.z, bfhi(gA2.x), acc.y);
                acc.z = fmaf(vA.z, bflo(gA2.y), acc.z); acc.w = fmaf(vA.z, bfhi(gA2.y), acc.w);
                acc.x = fmaf(vA.w, bflo(gA3.x), acc.x); acc.y = fmaf(vA.w, bfhi(gA3.x), acc.y);
                acc.z = fmaf(vA.w, bflo(gA3.y), acc.z); acc.w = fmaf(vA.w, bfhi(gA3.y), acc.w);
                vA = vB;
                gA0 = gB0; gA1 = gB1; gA2 = gB2; gA3 = gB3;
                j += 4;
            }
            acc.x = fmaf(vA.x, bflo(gA0.x), acc.x); acc.y = fmaf(vA.x, bfhi(gA0.x), acc.y);
            acc.z = fmaf(vA.x, bflo(gA0.y), acc.z); acc.w = fmaf(vA.x, bfhi(gA0.y), acc.w);
            acc.x = fmaf(vA.y, bflo(gA1.x), acc.x); acc.y = fmaf(vA.y, bfhi(gA1.x), acc.y);
            acc.z = fmaf(vA.y, bflo(gA1.y), acc.z); acc.w = fmaf(vA.y, bfhi(gA1.y), acc.w);
            acc.x = fmaf(vA.z, bflo(gA2.x), acc.x); acc.y = fmaf(vA.z, bfhi(gA2.x), acc.y);
            acc.z = fmaf(vA.z, bflo(gA2.y), acc.z); acc.w = fmaf(vA.z, bfhi(gA2.y), acc.w);
            acc.x = fmaf(vA.w, bflo(gA3.x), acc.x); acc.y = fmaf(vA.w, bfhi(gA3.x), acc.y);
            acc.z = fmaf(vA.w, bflo(gA3.y), acc.z); acc.w = fmaf(vA.w, bfhi(gA3.y), acc.w);
        }
        for (; j < e; j++) {
            uint2 g = h2[(size_t)col[j] * 4 + f];
            float v = vals[j];
            acc.x = fmaf(v, bflo(g.x), acc.x); acc.y = fmaf(v, bfhi(g.x), acc.y);
            acc.z = fmaf(v, bflo(g.y), acc.z); acc.w = fmaf(v, bfhi(g.y), acc.w);
        }
        if (BIAS) {
            float4 b = ((const float4*)bias)[f];
            acc.x += b.x; acc.y += b.y; acc.z += b.z; acc.w += b.w;
        }
        if (RELU) {
            acc.x = fmaxf(acc.x, 0.f); acc.y = fmaxf(acc.y, 0.f);
            acc.z = fmaxf(acc.z, 0.f); acc.w = fmaxf(acc.w, 0.f);
        }
        if (OBF) {
            uint2 o = {pk2(acc.x, acc.y), pk2(acc.z, acc.w)};
            ((uint2*)outv)[(size_t)node * 4 + f] = o;
        } else {
            ((float4*)outv)[(size_t)node * 4 + f] = acc;
        }
    }
    if (GRAM) {
        __shared__ float Us[64 * 20];
        int nl = threadIdx.x >> 2;
        float4 z = valid ? acc : (float4){0, 0, 0, 0};
        ((float4*)&Us[nl * 20])[f] = z;
        __syncthreads();
        int k = threadIdx.x & 15, kp = threadIdx.x >> 4;
        float g = 0.f, s = 0.f;
        for (int n = 0; n < 64; n++) {
            float a = Us[n * 20 + k];
            float b = Us[n * 20 + kp];
            g = fmaf(a, b, g);
            s += a;
        }
        float* gs = GS + (blockIdx.x & 7) * 272;   // 8 copies -> 8x less contention
        atomicAdd(&gs[kp * 16 + k], g);
        if (kp == 0) atomicAdd(&gs[256 + k], s);
    }
}

// ---- BN coefficients from Gram copies: SCSH[0..127]=sc, [128..255]=sh ----
__launch_bounds__(128)
__global__ void bn_prep(const float* __restrict__ GS, const float* __restrict__ W2,
                        const float* __restrict__ b2, const float* __restrict__ gamma,
                        const float* __restrict__ beta, float* __restrict__ SCSH) {
    __shared__ float Gs[272];
    int t = threadIdx.x;
    for (int i = t; i < 272; i += 128) {
        float a = 0.f;
        #pragma unroll
        for (int c = 0; c < 8; c++) a += GS[c * 272 + i];
        Gs[i] = a;
    }
    __syncthreads();
    int d = t;
    float w[16];
    #pragma unroll
    for (int k = 0; k < 16; k++) w[k] = W2[k * DD + d];
    float sdot = 0.f, quad = 0.f;
    #pragma unroll
    for (int k = 0; k < 16; k++) {
        sdot = fmaf(Gs[256 + k], w[k], sdot);
        float vk = 0.f;
        #pragma unroll
        for (int kp = 0; kp < 16; kp++) vk = fmaf(Gs[k * 16 + kp], w[kp], vk);
        quad = fmaf(w[k], vk, quad);
    }
    float b = b2[d];
    float sumH  = sdot + (float)NN * b;
    float sumsq = quad + 2.f * b * sdot + (float)NN * b * b;
    float mean = sumH * (1.f / NN);
    float var  = sumsq * (1.f / NN) - mean * mean;
    float inv  = rsqrtf(var + 1e-5f);
    float gm = gamma[d] * inv;
    SCSH[d] = gm;
    SCSH[128 + d] = (b - mean) * gm + beta[d];
}

// ---- Y(bf16) = relu(BN(U@W2)) @ W1n ; 8 lanes/node x 2 nodes/thread,
//      64 nodes/block (1563 blocks), BN coeffs precomputed ----
__launch_bounds__(256)
__global__ void fused_mid(const float* __restrict__ U, const float* __restrict__ SCSH,
                          const float* __restrict__ W2, const float* __restrict__ W1n,
                          unsigned* __restrict__ Y) {
    __shared__ float4 W2s[HH * 32];      // (k,dw) at k*32 + permW2(dw)
    __shared__ float4 W1s[DD * 4];       // (d,q)  at d*4 + ((q + (d>>4)) & 3)
    __shared__ float4 SC4[32], SH4[32];  // permW2 layout
    int t = threadIdx.x;
    for (int i = t; i < HH * 32; i += 256) {
        int k = i >> 5, dw = i & 31;
        W2s[k * 32 + permW2(dw)] = ((const float4*)W2)[i];
    }
    for (int i = t; i < DD * 4; i += 256) {
        int d = i >> 2, q = i & 3;
        W1s[d * 4 + ((q + (d >> 4)) & 3)] = ((const float4*)W1n)[i];
    }
    if (t < 32) SC4[permW2(t)] = ((const float4*)SCSH)[t];
    else if (t < 64) SH4[permW2(t - 32)] = ((const float4*)SCSH)[t];
    __syncthreads();
    int g = t >> 3, p = t & 7;
    int base = blockIdx.x * 64;
    int n[2]; bool v[2];
    #pragma unroll
    for (int i = 0; i < 2; i++) { n[i] = base + i * 32 + g; v[i] = n[i] < NN; }
    float u[2][16];
    #pragma unroll
    for (int i = 0; i < 2; i++) {
        if (v[i]) {
            const float4* up = (const float4*)(U + (size_t)n[i] * HH);
            float4 a = up[0], b = up[1], c = up[2], d = up[3];
            u[i][0]=a.x; u[i][1]=a.y; u[i][2]=a.z; u[i][3]=a.w;
            u[i][4]=b.x; u[i][5]=b.y; u[i][6]=b.z; u[i][7]=b.w;
            u[i][8]=c.x; u[i][9]=c.y; u[i][10]=c.z; u[i][11]=c.w;
            u[i][12]=d.x; u[i][13]=d.y; u[i][14]=d.z; u[i][15]=d.w;
        } else {
            #pragma unroll
            for (int k = 0; k < 16; k++) u[i][k] = 0.f;
        }
    }
    float4 y[2][4];
    #pragma unroll
    for (int i = 0; i < 2; i++)
        #pragma unroll
        for (int q = 0; q < 4; q++) y[i][q] = {0, 0, 0, 0};
    #pragma unroll
    for (int dqi = 0; dqi < 4; dqi++) {
        int rpos = p + (dqi << 3);        // permW2(p*4+dqi)
        float4 h[2] = {{0,0,0,0},{0,0,0,0}};
        #pragma unroll
        for (int k = 0; k < 16; k++) {
            float4 w = W2s[k * 32 + rpos];
            h[0] = f4fma(u[0][k], w, h[0]);
            h[1] = f4fma(u[1][k], w, h[1]);
        }
        float4 s4 = SC4[rpos], t4 = SH4[rpos];
        #pragma unroll
        for (int i = 0; i < 2; i++) {
            h[i].x = fmaxf(fmaf(h[i].x, s4.x, t4.x), 0.f);
            h[i].y = fmaxf(fmaf(h[i].y, s4.y, t4.y), 0.f);
            h[i].z = fmaxf(fmaf(h[i].z, s4.z, t4.z), 0.f);
            h[i].w = fmaxf(fmaf(h[i].w, s4.w, t4.w), 0.f);
        }
        int dq = (p << 2) + dqi;
        #pragma unroll
        for (int j = 0; j < 4; j++) {
            int d = (dq << 2) + j;
            float4 w0 = W1s[d * 4 + ((0 + p) & 3)];
            float4 w1 = W1s[d * 4 + ((1 + p) & 3)];
            float4 w2 = W1s[d * 4 + ((2 + p) & 3)];
            float4 w3 = W1s[d * 4 + ((3 + p) & 3)];
            float h0 = j == 0 ? h[0].x : j == 1 ? h[0].y : j == 2 ? h[0].z : h[0].w;
            float h1 = j == 0 ? h[1].x : j == 1 ? h[1].y : j == 2 ? h[1].z : h[1].w;
            y[0][0] = f4fma(h0, w0, y[0][0]); y[0][1] = f4fma(h0, w1, y[0][1]);
            y[0][2] = f4fma(h0, w2, y[0][2]); y[0][3] = f4fma(h0, w3, y[0][3]);
            y[1][0] = f4fma(h1, w0, y[1][0]); y[1][1] = f4fma(h1, w1, y[1][1]);
            y[1][2] = f4fma(h1, w2, y[1][2]); y[1][3] = f4fma(h1, w3, y[1][3]);
        }
    }
    #pragma unroll
    for (int i = 0; i < 2; i++)
        #pragma unroll
        for (int q = 0; q < 4; q++) {
            float4& a = y[i][q];
            a.x += __shfl_xor(a.x, 1); a.y += __shfl_xor(a.y, 1);
            a.z += __shfl_xor(a.z, 1); a.w += __shfl_xor(a.w, 1);
            a.x += __shfl_xor(a.x, 2); a.y += __shfl_xor(a.y, 2);
            a.z += __shfl_xor(a.z, 2); a.w += __shfl_xor(a.w, 2);
            a.x += __shfl_xor(a.x, 4); a.y += __shfl_xor(a.y, 4);
            a.z += __shfl_xor(a.z, 4); a.w += __shfl_xor(a.w, 4);
        }
    int wi = p >> 2, q = p & 3;
    if (v[wi]) {
        float4 a = y[wi][q];
        uint2 o = {pk2(a.x, a.y), pk2(a.z, a.w)};
        ((uint2*)Y)[(size_t)n[wi] * 4 + q] = o;
    }
}

// ---- out = U @ W + bias (N x 16)@(16 x 40); 4 threads/node, 10 cols each ----
__launch_bounds__(256)
__global__ void gemm_hc_reg(const float* __restrict__ U, const float* __restrict__ W,
                            const float* __restrict__ bias, float* __restrict__ out) {
    __shared__ float2 Ws[HH * 20];
    __shared__ float2 Bs[20];
    int t = threadIdx.x;
    for (int i = t; i < HH * 20; i += 256) Ws[i] = ((const float2*)W)[i];
    if (t < 20) Bs[t] = ((const float2*)bias)[t];
    __syncthreads();
    int node = blockIdx.x * 64 + (t >> 2);
    int p = t & 3;
    if (node >= NN) return;
    float u[16];
    {
        const float4* up = (const float4*)(U + (size_t)node * HH);
        float4 a = up[0], b = up[1], c = up[2], d = up[3];
        u[0]=a.x; u[1]=a.y; u[2]=a.z; u[3]=a.w; u[4]=b.x; u[5]=b.y; u[6]=b.z; u[7]=b.w;
        u[8]=c.x; u[9]=c.y; u[10]=c.z; u[11]=c.w; u[12]=d.x; u[13]=d.y; u[14]=d.z; u[15]=d.w;
    }
    float2 acc[5];
    #pragma unroll
    for (int i = 0; i < 5; i++) acc[i] = Bs[p * 5 + i];
    #pragma unroll
    for (int k = 0; k < 16; k++) {
        float uk = u[k];
        #pragma unroll
        for (int i = 0; i < 5; i++) {
            float2 w = Ws[k * 20 + p * 5 + i];
            acc[i].x = fmaf(uk, w.x, acc[i].x);
            acc[i].y = fmaf(uk, w.y, acc[i].y);
        }
    }
    float2* O = (float2*)(out + (size_t)node * CC) + p * 5;
    #pragma unroll
    for (int i = 0; i < 5; i++) O[i] = acc[i];
}

extern "C" void kernel_launch(void* const* d_in, const int* in_sizes, int n_in,
                              void* d_out, int out_size, void* d_ws, size_t ws_size,
                              hipStream_t stream) {
    const float* x     = (const float*)d_in[0];
    const float* vals  = (const float*)d_in[1];
    const float* W1    = (const float*)d_in[2];
    const float* b1    = (const float*)d_in[3];
    const float* W2    = (const float*)d_in[4];
    const float* b2    = (const float*)d_in[5];
    const float* gamma = (const float*)d_in[6];
    const float* beta  = (const float*)d_in[7];
    const float* W1f   = (const float*)d_in[8];
    const float* b1f   = (const float*)d_in[9];
    const float* W2f   = (const float*)d_in[10];
    const float* b2f   = (const float*)d_in[11];
    const int*   row   = (const int*)d_in[12];
    const int*   col   = (const int*)d_in[13];
    float* out = (float*)d_out;

    char* ws = (char*)d_ws;
    size_t off = 0;
    auto alloc = [&](size_t bytes) -> char* {
        char* p = ws + off;
        off += (bytes + 255) / 256 * 256;
        return p;
    };
    int*      rp   = (int*)     alloc((NN + 1) * sizeof(int));
    float*    GSC  = (float*)   alloc((size_t)LL * 8 * 272 * sizeof(float));
    float*    SCSH = (float*)   alloc(256 * sizeof(float));
    unsigned* Yb   = (unsigned*)alloc((size_t)NN * HH * 2);   // bf16
    unsigned* Tb   = (unsigned*)alloc((size_t)NN * HH * 2);   // bf16
    float*    U    = (float*)   alloc((size_t)NN * HH * sizeof(float));

    build_rowptr<<<(NE + 255) / 256, 256, 0, stream>>>(row, rp);
    zero_buf<<<(LL * 8 * 272 + 255) / 256, 256, 0, stream>>>(GSC, LL * 8 * 272);

    gemm_dh_reg<<<(NN + 255) / 256, 256, 0, stream>>>(x, W1, Yb);
    for (int l = 0; l < LL; l++) {
        spmm16<true, true, true, false><<<(NN + 63) / 64, 256, 0, stream>>>(
            rp, col, vals, Yb, b1 + l * HH, Tb, nullptr);
        spmm16<false, false, false, true><<<(NN + 63) / 64, 256, 0, stream>>>(
            rp, col, vals, Tb, nullptr, U, GSC + (size_t)l * 8 * 272);
        bn_prep<<<1, 128, 0, stream>>>(GSC + (size_t)l * 8 * 272, W2 + l * HH * DD,
                                       b2 + l * DD, gamma + l * DD, beta + l * DD, SCSH);
        const float* W1next = (l < LL - 1) ? (W1 + (l + 1) * DD * HH) : W1f;
        fused_mid<<<(NN + 63) / 64, 256, 0, stream>>>(U, SCSH, W2 + l * HH * DD, W1next, Yb);
    }
    spmm16<true, true, true, false><<<(NN + 63) / 64, 256, 0, stream>>>(
        rp, col, vals, Yb, b1f, Tb, nullptr);
    spmm16<false, false, false, false><<<(NN + 63) / 64, 256, 0, stream>>>(
        rp, col, vals, Tb, nullptr, U, nullptr);
    gemm_hc_reg<<<(NN + 63) / 64, 256, 0, stream>>>(U, W2f, b2f, out);
}